// Round 6
// baseline (353.347 us; speedup 1.0000x reference)
//
#include <hip/hip_runtime.h>
#include <stdint.h>

#define BB 4
#define SS 2048
#define EE 1024
#define HH 16
#define DD 64
#define MM (BB*SS)   // 8192

typedef unsigned short u16;
typedef __attribute__((ext_vector_type(8))) short bf16x8;
typedef __attribute__((ext_vector_type(4))) float f32x4;

#define MFMA __builtin_amdgcn_mfma_f32_16x16x32_bf16

__device__ __forceinline__ u16 f2bf(float f) {
  union { float f; uint32_t u; } x; x.f = f;
  uint32_t r = (x.u + 0x7fffu + ((x.u >> 16) & 1u)) >> 16;
  return (u16)r;
}

__device__ __forceinline__ uint32_t cvtpk(float lo, float hi) {
  uint32_t r;
  asm volatile("v_cvt_pk_bf16_f32 %0, %1, %2" : "=v"(r) : "v"(lo), "v"(hi));
  return r;
}

__device__ __forceinline__ void gl_lds16(const void* g, void* l) {
  __builtin_amdgcn_global_load_lds(
      (const __attribute__((address_space(1))) uint32_t*)g,
      (__attribute__((address_space(3))) uint32_t*)l, 16, 0, 0);
}

// ---------------- merged casts fp32 -> bf16 ----------------
__global__ __launch_bounds__(256) void cast3(
    const float* __restrict__ s0, const float* __restrict__ s1,
    const float* __restrict__ s2, u16* __restrict__ d0,
    u16* __restrict__ d1, u16* __restrict__ d2) {
  int i = blockIdx.x * 256 + threadIdx.x;          // i in [0, 3*2^20)
  int sel = i >> 20, off = i & ((1 << 20) - 1);
  const float* s = sel == 0 ? s0 : sel == 1 ? s1 : s2;
  u16* d = sel == 0 ? d0 : sel == 1 ? d1 : d2;
  const float4* sp = (const float4*)s;
  float4 a = sp[off*2], b = sp[off*2+1];
  union { u16 h[8]; uint4 v; } o;
  o.h[0]=f2bf(a.x); o.h[1]=f2bf(a.y); o.h[2]=f2bf(a.z); o.h[3]=f2bf(a.w);
  o.h[4]=f2bf(b.x); o.h[5]=f2bf(b.y); o.h[6]=f2bf(b.z); o.h[7]=f2bf(b.w);
  *(uint4*)(d + (size_t)off*8) = o.v;
}

__global__ __launch_bounds__(256) void cast4(
    const float* __restrict__ s0, const float* __restrict__ s1,
    const float* __restrict__ s2, const float* __restrict__ s3,
    u16* __restrict__ d0, u16* __restrict__ d1,
    u16* __restrict__ d2, u16* __restrict__ d3) {
  int i = blockIdx.x * 256 + threadIdx.x;          // i in [0, 4*2^17)
  int sel = i >> 17, off = i & ((1 << 17) - 1);
  const float* s = sel == 0 ? s0 : sel == 1 ? s1 : sel == 2 ? s2 : s3;
  u16* d = sel == 0 ? d0 : sel == 1 ? d1 : sel == 2 ? d2 : d3;
  const float4* sp = (const float4*)s;
  float4 a = sp[off*2], b = sp[off*2+1];
  union { u16 h[8]; uint4 v; } o;
  o.h[0]=f2bf(a.x); o.h[1]=f2bf(a.y); o.h[2]=f2bf(a.z); o.h[3]=f2bf(a.w);
  o.h[4]=f2bf(b.x); o.h[5]=f2bf(b.y); o.h[6]=f2bf(b.z); o.h[7]=f2bf(b.w);
  *(uint4*)(d + (size_t)off*8) = o.v;
}

// ---------------- GEMM core (R4-verified structure) ----------------
template<int OUT_BF16>
__device__ __forceinline__ void gemm_body(
    const u16* __restrict__ A, const u16* __restrict__ W,
    const float* __restrict__ bias, void* __restrict__ Cout,
    int Ndim, int Kdim, float scale, int m0, int n0,
    u16* As, u16* Bs) {
  const int tid = threadIdx.x;
  const int lane = tid & 63, w = tid >> 6;
  const int wr = w >> 1, wc = w & 1;
  const int srow = tid >> 2;
  const int scol = (tid & 3) * 8;

  f32x4 acc[4][4] = {};

  const u16* ag = A + (size_t)(m0 + srow) * Kdim + scol;
  const u16* bg = W + (size_t)(n0 + srow) * Kdim + scol;
  const size_t rstride = (size_t)64 * Kdim;
  const int l15 = lane & 15;
  const int fke = (lane >> 4) * 8;

  for (int k0 = 0; k0 < Kdim; k0 += 32) {
    gl_lds16(ag + k0,           As + tid*8);
    gl_lds16(ag + k0 + rstride, As + 2048 + tid*8);
    gl_lds16(bg + k0,           Bs + tid*8);
    gl_lds16(bg + k0 + rstride, Bs + 2048 + tid*8);
    __syncthreads();

    bf16x8 af[4], bfr[4];
    #pragma unroll
    for (int m = 0; m < 4; ++m)
      af[m] = *(const bf16x8*)(As + (wr*64 + m*16 + l15)*32 + fke);
    #pragma unroll
    for (int n = 0; n < 4; ++n)
      bfr[n] = *(const bf16x8*)(Bs + (wc*64 + n*16 + l15)*32 + fke);
    #pragma unroll
    for (int m = 0; m < 4; ++m)
      #pragma unroll
      for (int n = 0; n < 4; ++n)
        acc[m][n] = MFMA(af[m], bfr[n], acc[m][n], 0, 0, 0);
    __syncthreads();
  }

  const int ccol = wc*64 + l15;
  float bv[4];
  #pragma unroll
  for (int n = 0; n < 4; ++n) bv[n] = bias[n0 + ccol + n*16];
  #pragma unroll
  for (int m = 0; m < 4; ++m) {
    #pragma unroll
    for (int i = 0; i < 4; ++i) {
      size_t row = (size_t)(m0 + wr*64 + m*16 + (lane>>4)*4 + i);
      #pragma unroll
      for (int n = 0; n < 4; ++n) {
        float v = (acc[m][n][i] + bv[n]) * scale;
        size_t idx = row * Ndim + (n0 + ccol + n*16);
        if (OUT_BF16) ((u16*)Cout)[idx] = f2bf(v);
        else          ((float*)Cout)[idx] = v;
      }
    }
  }
}

// merged Q/K/V projections: z selects tensor set
__global__ __launch_bounds__(256, 2) void gemm_qkv(
    const u16* __restrict__ qx, const u16* __restrict__ kx, const u16* __restrict__ vx,
    const u16* __restrict__ wqm, const u16* __restrict__ wkm, const u16* __restrict__ wvm,
    const float* __restrict__ qbv, const float* __restrict__ kbv, const float* __restrict__ vbv,
    u16* __restrict__ qo, u16* __restrict__ ko, u16* __restrict__ vo) {
  __shared__ alignas(16) u16 As[128*32];
  __shared__ alignas(16) u16 Bs[128*32];
  const int z = blockIdx.z;
  const u16* A = z == 0 ? qx : z == 1 ? kx : vx;
  const u16* W = z == 0 ? wqm : z == 1 ? wkm : wvm;
  const float* bias = z == 0 ? qbv : z == 1 ? kbv : vbv;
  u16* C = z == 0 ? qo : z == 1 ? ko : vo;
  const float scale = z == 0 ? 0.125f : 1.0f;
  gemm_body<1>(A, W, bias, C, EE, EE, scale, blockIdx.y * 128, blockIdx.x * 128, As, Bs);
}

__global__ __launch_bounds__(256, 2) void gemm_out(
    const u16* __restrict__ A, const u16* __restrict__ W,
    const float* __restrict__ bias, float* __restrict__ Cout) {
  __shared__ alignas(16) u16 As[128*32];
  __shared__ alignas(16) u16 Bs[128*32];
  gemm_body<0>(A, W, bias, Cout, EE, EE, 1.0f, blockIdx.y * 128, blockIdx.x * 128, As, Bs);
}

// ---------------- causal flash attention v5 ----------------
// grid 1024 blocks (XCD-swizzled (qb,h,b) mapping), 256 thr, wave w owns 32 q.
// LDS = 40960 B exactly -> 4 blocks/CU, ONE barrier per tile:
//   Ks:  dbuf [2][64*64], 16B-slot ^ (kv&7)      (R4-verified)
//   VTs: dbuf [2][64*64], subtile swizzle        (R5-verified)
//   Ps:  [4][16*64] per-wave, G0/G1 time-multiplexed (R4-verified swizzle)
// Fixed-max softmax exp(s-12), per-lane partial lsum, deferred reduction.
__global__ __launch_bounds__(256, 4) void attn5(
    const u16* __restrict__ Q, const u16* __restrict__ K,
    const u16* __restrict__ V, u16* __restrict__ ctx) {
  __shared__ alignas(16) u16 Ks[2][64*64];    // 16384 B
  __shared__ alignas(16) u16 VTs[2][64*64];   // 16384 B
  __shared__ alignas(16) u16 Ps[4][16*64];    //  8192 B

  const int tid = threadIdx.x, lane = tid & 63, w = tid >> 6;
  const int l15 = lane & 15, l4 = lane >> 4;

  // XCD-aware swizzle (bijective: 1024 % 8 == 0). Consecutive qb-blocks of the
  // same (b,h) panel land on one XCD: each XCD holds 8 K/V panels = 4 MB = L2.
  const int flat = blockIdx.x + (blockIdx.y << 4) + (blockIdx.z << 8);
  const int swz = (flat & 7) * 128 + (flat >> 3);
  const int qb = swz & 15, h = (swz >> 4) & 15, b = swz >> 8;

  const int q0 = qb * 128, wq = q0 + w * 32;
  const size_t base = ((size_t)b * SS) * EE + h * DD;
  const int ntile = 2 * qb + 2;

  // Q B-frags (pre-scaled by 1/8 in projection)
  bf16x8 qf[2][2];
  #pragma unroll
  for (int G = 0; G < 2; ++G)
    #pragma unroll
    for (int kc = 0; kc < 2; ++kc)
      qf[G][kc] = *(const bf16x8*)(Q + base + (size_t)(wq + G*16 + l15)*EE + kc*32 + l4*8);

  f32x4 o[2][4] = {};
  float lsum[2] = {0.f, 0.f};

  const int kr  = tid >> 3;         // K-stage row within 32-row half
  const int ksl = tid & 7;          // K-stage 16B slot
  const int rv  = tid >> 2;         // V-load kv row 0..63
  const int vc  = tid & 3;          // V-load d chunk index (d0 = vc*16)

  u16* KsE  = (u16*)Ks;
  u16* VTsE = (u16*)VTs;
  u16* PsE  = (u16*)Ps + w * 1024;  // per-wave 16 rows x 64 (2048 B)

  auto stageK = [&](int t, int bi) {
    #pragma unroll
    for (int i = 0; i < 2; ++i) {
      int row = i*32 + kr;
      gl_lds16(K + base + (size_t)(t*64 + row)*EE + (ksl ^ (row & 7))*8,
               KsE + bi*4096 + i*2048 + tid*8);
    }
  };
  auto vtWrite = [&](int bi, bf16x8 v0, bf16x8 v1) {
    #pragma unroll
    for (int jj = 0; jj < 16; ++jj) {
      u16 val = jj < 8 ? (u16)v0[jj] : (u16)v1[jj - 8];
      int d = vc*16 + jj;
      int sl = (rv >> 3) ^ (jj & 7) ^ (vc << 1);   // (d&7)=jj&7, (d>>4)=vc
      VTsE[bi*4096 + d*64 + sl*8 + (rv & 7)] = val;
    }
  };

  // ---- prologue: stage tile 0 into buffers 0 ----
  {
    const u16* vs = V + base + (size_t)rv*EE + vc*16;
    bf16x8 v0 = *(const bf16x8*)vs;
    bf16x8 v1 = *(const bf16x8*)(vs + 8);
    stageK(0, 0);
    vtWrite(0, v0, v1);
  }
  __syncthreads();

  for (int t = 0; t < ntile; ++t) {
    const int cur = t & 1;
    const bool havenext = (t + 1 < ntile);
    bf16x8 nv0, nv1;
    if (havenext) {
      const u16* vs = V + base + (size_t)((t+1)*64 + rv)*EE + vc*16;
      nv0 = *(const bf16x8*)vs;
      nv1 = *(const bf16x8*)(vs + 8);
      stageK(t + 1, cur ^ 1);
    }

    const bool active = (wq + 31 >= t*64);
    const bool g0act  = (wq + 15 >= t*64);

    f32x4 sc[2][4];
    if (active) {
      // ---- QK^T (swapped): A = K rows, B = Q cols (R4-verified) ----
      #pragma unroll
      for (int G = 0; G < 2; ++G)
        #pragma unroll
        for (int nt = 0; nt < 4; ++nt) sc[G][nt] = f32x4{0.f,0.f,0.f,0.f};
      __builtin_amdgcn_s_setprio(1);
      #pragma unroll
      for (int nt = 0; nt < 4; ++nt) {
        int row = nt*16 + l15;
        int sw = row & 7;
        const u16* kb = KsE + cur*4096 + row*64;
        bf16x8 kf0 = *(const bf16x8*)(kb + ((l4    ) ^ sw)*8);
        bf16x8 kf1 = *(const bf16x8*)(kb + ((4 + l4) ^ sw)*8);
        sc[1][nt] = MFMA(kf0, qf[1][0], sc[1][nt], 0, 0, 0);
        sc[1][nt] = MFMA(kf1, qf[1][1], sc[1][nt], 0, 0, 0);
        if (g0act) {
          sc[0][nt] = MFMA(kf0, qf[0][0], sc[0][nt], 0, 0, 0);
          sc[0][nt] = MFMA(kf1, qf[0][1], sc[0][nt], 0, 0, 0);
        }
      }
      __builtin_amdgcn_s_setprio(0);
    }

    // V^T staging for next tile -> other buffer (overlaps with softmax/PV)
    if (havenext) vtWrite(cur ^ 1, nv0, nv1);

    if (active) {
      // ================= G = 1 (always active when wave active) =============
      {
        const bool nomask = (t*64 + 63 <= wq + 16);
        const int qg = wq + 16 + l15;
        #pragma unroll
        for (int nt = 0; nt < 4; ++nt) {
          float p0 = exp2f(__builtin_fmaf(sc[1][nt][0], 1.44269504f, -17.3123405f));
          float p1 = exp2f(__builtin_fmaf(sc[1][nt][1], 1.44269504f, -17.3123405f));
          float p2 = exp2f(__builtin_fmaf(sc[1][nt][2], 1.44269504f, -17.3123405f));
          float p3 = exp2f(__builtin_fmaf(sc[1][nt][3], 1.44269504f, -17.3123405f));
          if (!nomask) {
            int kvs = t*64 + nt*16 + l4*4;
            if (kvs + 0 > qg) p0 = 0.f;
            if (kvs + 1 > qg) p1 = 0.f;
            if (kvs + 2 > qg) p2 = 0.f;
            if (kvs + 3 > qg) p3 = 0.f;
          }
          lsum[1] += (p0 + p1) + (p2 + p3);
          uint2 pk;
          pk.x = cvtpk(p0, p1);
          pk.y = cvtpk(p2, p3);
          *(uint2*)((char*)PsE + l15*128
                        + (((nt*2 + (l4 >> 1)) ^ (l15 & 7)) * 16)
                        + (l4 & 1) * 8) = pk;
        }
        __builtin_amdgcn_s_setprio(1);
        #pragma unroll
        for (int cc = 0; cc < 2; ++cc) {
          bf16x8 pfv = *(const bf16x8*)((char*)PsE + l15*128
                                       + (((cc*4 + l4) ^ (l15 & 7)) * 16));
          #pragma unroll
          for (int dm = 0; dm < 4; ++dm) {
            int sl = (cc*4 + l4) ^ (l15 & 7) ^ (dm << 1);
            bf16x8 vfv = *(const bf16x8*)(VTsE + cur*4096 + (dm*16 + l15)*64 + sl*8);
            o[1][dm] = MFMA(pfv, vfv, o[1][dm], 0, 0, 0);
          }
        }
        __builtin_amdgcn_s_setprio(0);
      }
      // ================= G = 0 (time-multiplexed P buffer) ==================
      if (g0act) {
        const bool nomask = (t*64 + 63 <= wq);
        const int qg = wq + l15;
        #pragma unroll
        for (int nt = 0; nt < 4; ++nt) {
          float p0 = exp2f(__builtin_fmaf(sc[0][nt][0], 1.44269504f, -17.3123405f));
          float p1 = exp2f(__builtin_fmaf(sc[0][nt][1], 1.44269504f, -17.3123405f));
          float p2 = exp2f(__builtin_fmaf(sc[0][nt][2], 1.44269504f, -17.3123405f));
          float p3 = exp2f(__builtin_fmaf(sc[0][nt][3], 1.44269504f, -17.3123405f));
          if (!nomask) {
            int kvs = t*64 + nt*16 + l4*4;
            if (kvs + 0 > qg) p0 = 0.f;
            if (kvs + 1 > qg) p1 = 0.f;
            if (kvs + 2 > qg) p2 = 0.f;
            if (kvs + 3 > qg) p3 = 0.f;
          }
          lsum[0] += (p0 + p1) + (p2 + p3);
          uint2 pk;
          pk.x = cvtpk(p0, p1);
          pk.y = cvtpk(p2, p3);
          *(uint2*)((char*)PsE + l15*128
                        + (((nt*2 + (l4 >> 1)) ^ (l15 & 7)) * 16)
                        + (l4 & 1) * 8) = pk;
        }
        __builtin_amdgcn_s_setprio(1);
        #pragma unroll
        for (int cc = 0; cc < 2; ++cc) {
          bf16x8 pfv = *(const bf16x8*)((char*)PsE + l15*128
                                       + (((cc*4 + l4) ^ (l15 & 7)) * 16));
          #pragma unroll
          for (int dm = 0; dm < 4; ++dm) {
            int sl = (cc*4 + l4) ^ (l15 & 7) ^ (dm << 1);
            bf16x8 vfv = *(const bf16x8*)(VTsE + cur*4096 + (dm*16 + l15)*64 + sl*8);
            o[0][dm] = MFMA(pfv, vfv, o[0][dm], 0, 0, 0);
          }
        }
        __builtin_amdgcn_s_setprio(0);
      }
    }
    __syncthreads();   // single barrier: dbuf writes (K,V) for t+1 + reads of cur done
  }

  // deferred l reduction (lane holds partial for q = l15; sum over l4 groups)
  #pragma unroll
  for (int G = 0; G < 2; ++G) {
    float r = lsum[G];
    r += __shfl_xor(r, 16);
    r += __shfl_xor(r, 32);
    lsum[G] = 1.0f / r;
  }

  // output: o[G][dm][i] at q = wq+G*16+l4*4+i, d = dm*16+l15
  #pragma unroll
  for (int G = 0; G < 2; ++G)
    #pragma unroll
    for (int i = 0; i < 4; ++i) {
      float invv = __shfl(lsum[G], l4*4 + i);
      size_t roff = base + (size_t)(wq + G*16 + l4*4 + i) * EE;
      #pragma unroll
      for (int dm = 0; dm < 4; ++dm)
        ctx[roff + dm*16 + l15] = f2bf(o[G][dm][i] * invv);
    }
}

// ---------------- launch ----------------
extern "C" void kernel_launch(void* const* d_in, const int* in_sizes, int n_in,
                              void* d_out, int out_size, void* d_ws, size_t ws_size,
                              hipStream_t stream) {
  const float* query = (const float*)d_in[0];
  const float* key   = (const float*)d_in[1];
  const float* value = (const float*)d_in[2];
  const float* q_w = (const float*)d_in[4];
  const float* q_b = (const float*)d_in[5];
  const float* k_w = (const float*)d_in[6];
  const float* k_b = (const float*)d_in[7];
  const float* v_w = (const float*)d_in[8];
  const float* v_b = (const float*)d_in[9];
  const float* o_w = (const float*)d_in[10];
  const float* o_b = (const float*)d_in[11];

  char* ws = (char*)d_ws;
  const size_t XB = (size_t)MM * EE * 2;
  const size_t WB = (size_t)EE * EE * 2;
  u16* qx = (u16*)(ws);
  u16* kx = (u16*)(ws + XB);
  u16* vx = (u16*)(ws + 2*XB);
  u16* wq = (u16*)(ws + 3*XB);
  u16* wk = (u16*)(ws + 3*XB + WB);
  u16* wv = (u16*)(ws + 3*XB + 2*WB);
  u16* wo = (u16*)(ws + 3*XB + 3*WB);
  u16* qp = (u16*)(ws + 3*XB + 4*WB);
  u16* kp = (u16*)(ws + 4*XB + 4*WB);
  u16* vp = (u16*)(ws + 5*XB + 4*WB);
  u16* ctxb = qx;   // reuse: query-cast dead after Q projection

  const int nx8 = MM * EE / 8;   // 2^20
  const int nw8 = EE * EE / 8;   // 2^17
  cast3<<<3*nx8/256, 256, 0, stream>>>(query, key, value, qx, kx, vx);
  cast4<<<4*nw8/256, 256, 0, stream>>>(q_w, k_w, v_w, o_w, wq, wk, wv, wo);

  gemm_qkv<<<dim3(EE/128, MM/128, 3), 256, 0, stream>>>(
      qx, kx, vx, wq, wk, wv, q_b, k_b, v_b, qp, kp, vp);

  attn5<<<dim3(SS/128, HH, BB), 256, 0, stream>>>(qp, kp, vp, ctxb);

  gemm_out<<<dim3(EE/128, MM/128), 256, 0, stream>>>(ctxb, wo, o_b, (float*)d_out);
}

// Round 7
// 255.512 us; speedup vs baseline: 1.3829x; 1.3829x over previous
//
#include <hip/hip_runtime.h>
#include <stdint.h>

#define BB 4
#define SS 2048
#define EE 1024
#define HH 16
#define DD 64
#define MM (BB*SS)   // 8192

typedef unsigned short u16;
typedef __attribute__((ext_vector_type(8))) short bf16x8;
typedef __attribute__((ext_vector_type(4))) float f32x4;

#define MFMA __builtin_amdgcn_mfma_f32_16x16x32_bf16

__device__ __forceinline__ u16 f2bf(float f) {
  union { float f; uint32_t u; } x; x.f = f;
  uint32_t r = (x.u + 0x7fffu + ((x.u >> 16) & 1u)) >> 16;
  return (u16)r;
}

__device__ __forceinline__ uint32_t cvtpk(float lo, float hi) {
  uint32_t r;
  asm volatile("v_cvt_pk_bf16_f32 %0, %1, %2" : "=v"(r) : "v"(lo), "v"(hi));
  return r;
}

__device__ __forceinline__ void gl_lds16(const void* g, void* l) {
  __builtin_amdgcn_global_load_lds(
      (const __attribute__((address_space(1))) uint32_t*)g,
      (__attribute__((address_space(3))) uint32_t*)l, 16, 0, 0);
}

// ---------------- merged casts fp32 -> bf16 ----------------
__global__ __launch_bounds__(256) void cast3(
    const float* __restrict__ s0, const float* __restrict__ s1,
    const float* __restrict__ s2, u16* __restrict__ d0,
    u16* __restrict__ d1, u16* __restrict__ d2) {
  int i = blockIdx.x * 256 + threadIdx.x;          // i in [0, 3*2^20)
  int sel = i >> 20, off = i & ((1 << 20) - 1);
  const float* s = sel == 0 ? s0 : sel == 1 ? s1 : s2;
  u16* d = sel == 0 ? d0 : sel == 1 ? d1 : d2;
  const float4* sp = (const float4*)s;
  float4 a = sp[off*2], b = sp[off*2+1];
  union { u16 h[8]; uint4 v; } o;
  o.h[0]=f2bf(a.x); o.h[1]=f2bf(a.y); o.h[2]=f2bf(a.z); o.h[3]=f2bf(a.w);
  o.h[4]=f2bf(b.x); o.h[5]=f2bf(b.y); o.h[6]=f2bf(b.z); o.h[7]=f2bf(b.w);
  *(uint4*)(d + (size_t)off*8) = o.v;
}

__global__ __launch_bounds__(256) void cast4(
    const float* __restrict__ s0, const float* __restrict__ s1,
    const float* __restrict__ s2, const float* __restrict__ s3,
    u16* __restrict__ d0, u16* __restrict__ d1,
    u16* __restrict__ d2, u16* __restrict__ d3) {
  int i = blockIdx.x * 256 + threadIdx.x;          // i in [0, 4*2^17)
  int sel = i >> 17, off = i & ((1 << 17) - 1);
  const float* s = sel == 0 ? s0 : sel == 1 ? s1 : sel == 2 ? s2 : s3;
  u16* d = sel == 0 ? d0 : sel == 1 ? d1 : sel == 2 ? d2 : d3;
  const float4* sp = (const float4*)s;
  float4 a = sp[off*2], b = sp[off*2+1];
  union { u16 h[8]; uint4 v; } o;
  o.h[0]=f2bf(a.x); o.h[1]=f2bf(a.y); o.h[2]=f2bf(a.z); o.h[3]=f2bf(a.w);
  o.h[4]=f2bf(b.x); o.h[5]=f2bf(b.y); o.h[6]=f2bf(b.z); o.h[7]=f2bf(b.w);
  *(uint4*)(d + (size_t)off*8) = o.v;
}

// ---------------- GEMM core (R4-verified structure) ----------------
template<int OUT_BF16>
__device__ __forceinline__ void gemm_body(
    const u16* __restrict__ A, const u16* __restrict__ W,
    const float* __restrict__ bias, void* __restrict__ Cout,
    int Ndim, int Kdim, float scale, int m0, int n0,
    u16* As, u16* Bs) {
  const int tid = threadIdx.x;
  const int lane = tid & 63, w = tid >> 6;
  const int wr = w >> 1, wc = w & 1;
  const int srow = tid >> 2;
  const int scol = (tid & 3) * 8;

  f32x4 acc[4][4] = {};

  const u16* ag = A + (size_t)(m0 + srow) * Kdim + scol;
  const u16* bg = W + (size_t)(n0 + srow) * Kdim + scol;
  const size_t rstride = (size_t)64 * Kdim;
  const int l15 = lane & 15;
  const int fke = (lane >> 4) * 8;

  for (int k0 = 0; k0 < Kdim; k0 += 32) {
    gl_lds16(ag + k0,           As + tid*8);
    gl_lds16(ag + k0 + rstride, As + 2048 + tid*8);
    gl_lds16(bg + k0,           Bs + tid*8);
    gl_lds16(bg + k0 + rstride, Bs + 2048 + tid*8);
    __syncthreads();

    bf16x8 af[4], bfr[4];
    #pragma unroll
    for (int m = 0; m < 4; ++m)
      af[m] = *(const bf16x8*)(As + (wr*64 + m*16 + l15)*32 + fke);
    #pragma unroll
    for (int n = 0; n < 4; ++n)
      bfr[n] = *(const bf16x8*)(Bs + (wc*64 + n*16 + l15)*32 + fke);
    #pragma unroll
    for (int m = 0; m < 4; ++m)
      #pragma unroll
      for (int n = 0; n < 4; ++n)
        acc[m][n] = MFMA(af[m], bfr[n], acc[m][n], 0, 0, 0);
    __syncthreads();
  }

  const int ccol = wc*64 + l15;
  float bv[4];
  #pragma unroll
  for (int n = 0; n < 4; ++n) bv[n] = bias[n0 + ccol + n*16];
  #pragma unroll
  for (int m = 0; m < 4; ++m) {
    #pragma unroll
    for (int i = 0; i < 4; ++i) {
      size_t row = (size_t)(m0 + wr*64 + m*16 + (lane>>4)*4 + i);
      #pragma unroll
      for (int n = 0; n < 4; ++n) {
        float v = (acc[m][n][i] + bv[n]) * scale;
        size_t idx = row * Ndim + (n0 + ccol + n*16);
        if (OUT_BF16) ((u16*)Cout)[idx] = f2bf(v);
        else          ((float*)Cout)[idx] = v;
      }
    }
  }
}

// merged Q/K/V projections with XCD chunk-swizzle:
// XCD j (= flat%8 round-robin) processes 3 chunks of 64 blocks; each chunk =
// all 8 n-panels x 8 m-panels of one tensor slice -> W 2MB + A 2MB = one L2.
// Chunk size 64 = one XCD's block capacity at 2 blocks/CU.
__global__ __launch_bounds__(256, 2) void gemm_qkv(
    const u16* __restrict__ qx, const u16* __restrict__ kx, const u16* __restrict__ vx,
    const u16* __restrict__ wqm, const u16* __restrict__ wkm, const u16* __restrict__ wvm,
    const float* __restrict__ qbv, const float* __restrict__ kbv, const float* __restrict__ vbv,
    u16* __restrict__ qo, u16* __restrict__ ko, u16* __restrict__ vo) {
  __shared__ alignas(16) u16 As[128*32];
  __shared__ alignas(16) u16 Bs[128*32];
  const int flat = blockIdx.x + blockIdx.y * 8 + blockIdx.z * 512;  // 0..1535
  const int j = flat & 7, s = flat >> 3;        // XCD, slot within XCD
  const int c = 3*j + (s >> 6), i = s & 63;     // chunk 0..23, block in chunk
  const int nx = i & 7, yy = ((c & 7) << 3) + (i >> 3);
  const int z = c >> 3;
  const u16* A = z == 0 ? qx : z == 1 ? kx : vx;
  const u16* W = z == 0 ? wqm : z == 1 ? wkm : wvm;
  const float* bias = z == 0 ? qbv : z == 1 ? kbv : vbv;
  u16* C = z == 0 ? qo : z == 1 ? ko : vo;
  const float scale = z == 0 ? 0.125f : 1.0f;
  gemm_body<1>(A, W, bias, C, EE, EE, scale, yy * 128, nx * 128, As, Bs);
}

__global__ __launch_bounds__(256, 2) void gemm_out(
    const u16* __restrict__ A, const u16* __restrict__ W,
    const float* __restrict__ bias, float* __restrict__ Cout) {
  __shared__ alignas(16) u16 As[128*32];
  __shared__ alignas(16) u16 Bs[128*32];
  const int flat = blockIdx.x + blockIdx.y * 8;   // 0..511
  const int j = flat & 7, s = flat >> 3;          // XCD, slot 0..63
  const int nx = s & 7, yy = (j << 3) + (s >> 3); // XCD j -> m-panels 8j..8j+7
  gemm_body<0>(A, W, bias, Cout, EE, EE, 1.0f, yy * 128, nx * 128, As, Bs);
}

// ---------------- causal flash attention v6 (R4 structure restored) --------
// grid (S/128, H, B), 256 thr, wave w owns 32 q rows (2 G-blocks of 16).
// Ks:  dbuf [2][64*64], 16B-slot ^ (kv&7)                  (R4-verified)
// VTs: dbuf [2][64*64], conflict-free subtile XOR layout   (R5-verified)
// Ps:  [4][32*64] per-wave, G0/G1 SEPARATE halves          (R4-verified)
// vtWrite overlapped with softmax/PV into other buffer, ONE barrier per tile.
// Fixed-max softmax exp(s-12), per-lane partial lsum, deferred reduction.
__global__ __launch_bounds__(256, 2) void attn6(
    const u16* __restrict__ Q, const u16* __restrict__ K,
    const u16* __restrict__ V, u16* __restrict__ ctx) {
  __shared__ alignas(16) u16 Ks[2][64*64];    // 16384 B
  __shared__ alignas(16) u16 VTs[2][64*64];   // 16384 B
  __shared__ alignas(16) u16 Ps[4][32*64];    // 16384 B  (49152 total, 3 blk/CU)

  const int tid = threadIdx.x, lane = tid & 63, w = tid >> 6;
  const int l15 = lane & 15, l4 = lane >> 4;
  const int qb = blockIdx.x, h = blockIdx.y, b = blockIdx.z;
  const int q0 = qb * 128, wq = q0 + w * 32;
  const size_t base = ((size_t)b * SS) * EE + h * DD;
  const int ntile = 2 * qb + 2;

  // Q B-frags (pre-scaled by 1/8 in projection)
  bf16x8 qf[2][2];
  #pragma unroll
  for (int G = 0; G < 2; ++G)
    #pragma unroll
    for (int kc = 0; kc < 2; ++kc)
      qf[G][kc] = *(const bf16x8*)(Q + base + (size_t)(wq + G*16 + l15)*EE + kc*32 + l4*8);

  f32x4 o[2][4] = {};
  float lsum[2] = {0.f, 0.f};

  const int kr  = tid >> 3;         // K-stage row within 32-row half
  const int ksl = tid & 7;          // K-stage 16B slot
  const int rv  = tid >> 2;         // V-load kv row 0..63
  const int vc  = tid & 3;          // V-load d chunk index (d0 = vc*16)

  u16* KsE  = (u16*)Ks;
  u16* VTsE = (u16*)VTs;
  u16* PsE  = (u16*)Ps + w * 2048;  // per-wave 32 rows x 64 (4096 B)

  auto stageK = [&](int t, int bi) {
    #pragma unroll
    for (int i = 0; i < 2; ++i) {
      int row = i*32 + kr;
      gl_lds16(K + base + (size_t)(t*64 + row)*EE + (ksl ^ (row & 7))*8,
               KsE + bi*4096 + i*2048 + tid*8);
    }
  };
  auto vtWrite = [&](int bi, bf16x8 v0, bf16x8 v1) {
    #pragma unroll
    for (int jj = 0; jj < 16; ++jj) {
      u16 val = jj < 8 ? (u16)v0[jj] : (u16)v1[jj - 8];
      int d = vc*16 + jj;
      int sl = (rv >> 3) ^ (jj & 7) ^ (vc << 1);   // (d&7)=jj&7, (d>>4)=vc
      VTsE[bi*4096 + d*64 + sl*8 + (rv & 7)] = val;
    }
  };

  // ---- prologue: stage tile 0 into buffers 0 ----
  {
    const u16* vs = V + base + (size_t)rv*EE + vc*16;
    bf16x8 v0 = *(const bf16x8*)vs;
    bf16x8 v1 = *(const bf16x8*)(vs + 8);
    stageK(0, 0);
    vtWrite(0, v0, v1);
  }
  __syncthreads();

  for (int t = 0; t < ntile; ++t) {
    const int cur = t & 1;
    const bool havenext = (t + 1 < ntile);
    bf16x8 nv0, nv1;
    if (havenext) {
      const u16* vs = V + base + (size_t)((t+1)*64 + rv)*EE + vc*16;
      nv0 = *(const bf16x8*)vs;
      nv1 = *(const bf16x8*)(vs + 8);
      stageK(t + 1, cur ^ 1);
    }

    const bool active = (wq + 31 >= t*64);
    const bool g0act  = (wq + 15 >= t*64);
    if (active) {
      // ---- QK^T (swapped): A = K rows, B = Q cols (R4-verified) ----
      f32x4 sc[2][4] = {};
      #pragma unroll
      for (int nt = 0; nt < 4; ++nt) {
        int row = nt*16 + l15;
        int sw = row & 7;
        const u16* kb = KsE + cur*4096 + row*64;
        bf16x8 kf0 = *(const bf16x8*)(kb + ((l4    ) ^ sw)*8);
        bf16x8 kf1 = *(const bf16x8*)(kb + ((4 + l4) ^ sw)*8);
        sc[1][nt] = MFMA(kf0, qf[1][0], sc[1][nt], 0, 0, 0);
        sc[1][nt] = MFMA(kf1, qf[1][1], sc[1][nt], 0, 0, 0);
        if (g0act) {
          sc[0][nt] = MFMA(kf0, qf[0][0], sc[0][nt], 0, 0, 0);
          sc[0][nt] = MFMA(kf1, qf[0][1], sc[0][nt], 0, 0, 0);
        }
      }

      // ---- fixed-max softmax + packed P write (both G, separate buffers) ----
      #pragma unroll
      for (int G = 0; G < 2; ++G) {
        if (G == 0 && !g0act) continue;
        const bool nomask = (t*64 + 63 <= wq + G*16);
        const int qg = wq + G*16 + l15;
        #pragma unroll
        for (int nt = 0; nt < 4; ++nt) {
          float p0 = exp2f(__builtin_fmaf(sc[G][nt][0], 1.44269504f, -17.3123405f));
          float p1 = exp2f(__builtin_fmaf(sc[G][nt][1], 1.44269504f, -17.3123405f));
          float p2 = exp2f(__builtin_fmaf(sc[G][nt][2], 1.44269504f, -17.3123405f));
          float p3 = exp2f(__builtin_fmaf(sc[G][nt][3], 1.44269504f, -17.3123405f));
          if (!nomask) {
            int kvs = t*64 + nt*16 + l4*4;
            if (kvs + 0 > qg) p0 = 0.f;
            if (kvs + 1 > qg) p1 = 0.f;
            if (kvs + 2 > qg) p2 = 0.f;
            if (kvs + 3 > qg) p3 = 0.f;
          }
          lsum[G] += (p0 + p1) + (p2 + p3);
          uint2 pk;
          pk.x = cvtpk(p0, p1);
          pk.y = cvtpk(p2, p3);
          *(uint2*)((char*)PsE + (G*16 + l15)*128
                        + (((nt*2 + (l4 >> 1)) ^ (l15 & 7)) * 16)
                        + (l4 & 1) * 8) = pk;
        }
      }
    }

    // V^T staging for next tile -> other buffer (overlaps with PV below)
    if (havenext) vtWrite(cur ^ 1, nv0, nv1);

    if (active) {
      // ---- PV: A = P rows (q=l15), B = V^T from swizzled VTs ----
      #pragma unroll
      for (int cc = 0; cc < 2; ++cc) {
        bf16x8 pf1 = *(const bf16x8*)((char*)PsE + (16 + l15)*128
                                     + (((cc*4 + l4) ^ (l15 & 7)) * 16));
        bf16x8 pf0;
        if (g0act)
          pf0 = *(const bf16x8*)((char*)PsE + l15*128
                                     + (((cc*4 + l4) ^ (l15 & 7)) * 16));
        #pragma unroll
        for (int dm = 0; dm < 4; ++dm) {
          int sl = (cc*4 + l4) ^ (l15 & 7) ^ (dm << 1);
          bf16x8 vfv = *(const bf16x8*)(VTsE + cur*4096 + (dm*16 + l15)*64 + sl*8);
          o[1][dm] = MFMA(pf1, vfv, o[1][dm], 0, 0, 0);
          if (g0act) o[0][dm] = MFMA(pf0, vfv, o[0][dm], 0, 0, 0);
        }
      }
    }
    __syncthreads();   // single barrier: t+1 staging (K gl_lds + V^T) visible
  }

  // deferred l reduction (lane holds partial for q = l15; sum over l4 groups)
  #pragma unroll
  for (int G = 0; G < 2; ++G) {
    float r = lsum[G];
    r += __shfl_xor(r, 16);
    r += __shfl_xor(r, 32);
    lsum[G] = 1.0f / r;
  }

  // output: o[G][dm][i] at q = wq+G*16+l4*4+i, d = dm*16+l15
  #pragma unroll
  for (int G = 0; G < 2; ++G)
    #pragma unroll
    for (int i = 0; i < 4; ++i) {
      float invv = __shfl(lsum[G], l4*4 + i);
      size_t roff = base + (size_t)(wq + G*16 + l4*4 + i) * EE;
      #pragma unroll
      for (int dm = 0; dm < 4; ++dm)
        ctx[roff + dm*16 + l15] = f2bf(o[G][dm][i] * invv);
    }
}

// ---------------- launch ----------------
extern "C" void kernel_launch(void* const* d_in, const int* in_sizes, int n_in,
                              void* d_out, int out_size, void* d_ws, size_t ws_size,
                              hipStream_t stream) {
  const float* query = (const float*)d_in[0];
  const float* key   = (const float*)d_in[1];
  const float* value = (const float*)d_in[2];
  const float* q_w = (const float*)d_in[4];
  const float* q_b = (const float*)d_in[5];
  const float* k_w = (const float*)d_in[6];
  const float* k_b = (const float*)d_in[7];
  const float* v_w = (const float*)d_in[8];
  const float* v_b = (const float*)d_in[9];
  const float* o_w = (const float*)d_in[10];
  const float* o_b = (const float*)d_in[11];

  char* ws = (char*)d_ws;
  const size_t XB = (size_t)MM * EE * 2;
  const size_t WB = (size_t)EE * EE * 2;
  u16* qx = (u16*)(ws);
  u16* kx = (u16*)(ws + XB);
  u16* vx = (u16*)(ws + 2*XB);
  u16* wq = (u16*)(ws + 3*XB);
  u16* wk = (u16*)(ws + 3*XB + WB);
  u16* wv = (u16*)(ws + 3*XB + 2*WB);
  u16* wo = (u16*)(ws + 3*XB + 3*WB);
  u16* qp = (u16*)(ws + 3*XB + 4*WB);
  u16* kp = (u16*)(ws + 4*XB + 4*WB);
  u16* vp = (u16*)(ws + 5*XB + 4*WB);
  u16* ctxb = qx;   // reuse: query-cast dead after Q projection

  const int nx8 = MM * EE / 8;   // 2^20
  const int nw8 = EE * EE / 8;   // 2^17
  cast3<<<3*nx8/256, 256, 0, stream>>>(query, key, value, qx, kx, vx);
  cast4<<<4*nw8/256, 256, 0, stream>>>(q_w, k_w, v_w, o_w, wq, wk, wv, wo);

  gemm_qkv<<<dim3(EE/128, MM/128, 3), 256, 0, stream>>>(
      qx, kx, vx, wq, wk, wv, q_b, k_b, v_b, qp, kp, vp);

  attn6<<<dim3(SS/128, HH, BB), 256, 0, stream>>>(qp, kp, vp, ctxb);

  gemm_out<<<dim3(EE/128, MM/128), 256, 0, stream>>>(ctxb, wo, o_b, (float*)d_out);
}

// Round 8
// 204.562 us; speedup vs baseline: 1.7273x; 1.2491x over previous
//
#include <hip/hip_runtime.h>
#include <stdint.h>

#define BB 4
#define SS 2048
#define EE 1024
#define HH 16
#define DD 64
#define MM (BB*SS)   // 8192

typedef unsigned short u16;
typedef __attribute__((ext_vector_type(8))) short bf16x8;
typedef __attribute__((ext_vector_type(4))) float f32x4;

#define MFMA __builtin_amdgcn_mfma_f32_16x16x32_bf16

__device__ __forceinline__ u16 f2bf(float f) {
  union { float f; uint32_t u; } x; x.f = f;
  uint32_t r = (x.u + 0x7fffu + ((x.u >> 16) & 1u)) >> 16;
  return (u16)r;
}

__device__ __forceinline__ uint32_t cvtpk(float lo, float hi) {
  uint32_t r;
  asm volatile("v_cvt_pk_bf16_f32 %0, %1, %2" : "=v"(r) : "v"(lo), "v"(hi));
  return r;
}

__device__ __forceinline__ void gl_lds16(const void* g, void* l) {
  __builtin_amdgcn_global_load_lds(
      (const __attribute__((address_space(1))) uint32_t*)g,
      (__attribute__((address_space(3))) uint32_t*)l, 16, 0, 0);
}

// ---------------- merged casts fp32 -> bf16 ----------------
__global__ __launch_bounds__(256) void cast3(
    const float* __restrict__ s0, const float* __restrict__ s1,
    const float* __restrict__ s2, u16* __restrict__ d0,
    u16* __restrict__ d1, u16* __restrict__ d2) {
  int i = blockIdx.x * 256 + threadIdx.x;          // i in [0, 3*2^20)
  int sel = i >> 20, off = i & ((1 << 20) - 1);
  const float* s = sel == 0 ? s0 : sel == 1 ? s1 : s2;
  u16* d = sel == 0 ? d0 : sel == 1 ? d1 : d2;
  const float4* sp = (const float4*)s;
  float4 a = sp[off*2], b = sp[off*2+1];
  union { u16 h[8]; uint4 v; } o;
  o.h[0]=f2bf(a.x); o.h[1]=f2bf(a.y); o.h[2]=f2bf(a.z); o.h[3]=f2bf(a.w);
  o.h[4]=f2bf(b.x); o.h[5]=f2bf(b.y); o.h[6]=f2bf(b.z); o.h[7]=f2bf(b.w);
  *(uint4*)(d + (size_t)off*8) = o.v;
}

__global__ __launch_bounds__(256) void cast4(
    const float* __restrict__ s0, const float* __restrict__ s1,
    const float* __restrict__ s2, const float* __restrict__ s3,
    u16* __restrict__ d0, u16* __restrict__ d1,
    u16* __restrict__ d2, u16* __restrict__ d3) {
  int i = blockIdx.x * 256 + threadIdx.x;          // i in [0, 4*2^17)
  int sel = i >> 17, off = i & ((1 << 17) - 1);
  const float* s = sel == 0 ? s0 : sel == 1 ? s1 : sel == 2 ? s2 : s3;
  u16* d = sel == 0 ? d0 : sel == 1 ? d1 : sel == 2 ? d2 : d3;
  const float4* sp = (const float4*)s;
  float4 a = sp[off*2], b = sp[off*2+1];
  union { u16 h[8]; uint4 v; } o;
  o.h[0]=f2bf(a.x); o.h[1]=f2bf(a.y); o.h[2]=f2bf(a.z); o.h[3]=f2bf(a.w);
  o.h[4]=f2bf(b.x); o.h[5]=f2bf(b.y); o.h[6]=f2bf(b.z); o.h[7]=f2bf(b.w);
  *(uint4*)(d + (size_t)off*8) = o.v;
}

// ---------------- GEMM core (R4-verified structure) ----------------
template<int OUT_BF16>
__device__ __forceinline__ void gemm_body(
    const u16* __restrict__ A, const u16* __restrict__ W,
    const float* __restrict__ bias, void* __restrict__ Cout,
    int Ndim, int Kdim, float scale, int m0, int n0,
    u16* As, u16* Bs) {
  const int tid = threadIdx.x;
  const int lane = tid & 63, w = tid >> 6;
  const int wr = w >> 1, wc = w & 1;
  const int srow = tid >> 2;
  const int scol = (tid & 3) * 8;

  f32x4 acc[4][4] = {};

  const u16* ag = A + (size_t)(m0 + srow) * Kdim + scol;
  const u16* bg = W + (size_t)(n0 + srow) * Kdim + scol;
  const size_t rstride = (size_t)64 * Kdim;
  const int l15 = lane & 15;
  const int fke = (lane >> 4) * 8;

  for (int k0 = 0; k0 < Kdim; k0 += 32) {
    gl_lds16(ag + k0,           As + tid*8);
    gl_lds16(ag + k0 + rstride, As + 2048 + tid*8);
    gl_lds16(bg + k0,           Bs + tid*8);
    gl_lds16(bg + k0 + rstride, Bs + 2048 + tid*8);
    __syncthreads();

    bf16x8 af[4], bfr[4];
    #pragma unroll
    for (int m = 0; m < 4; ++m)
      af[m] = *(const bf16x8*)(As + (wr*64 + m*16 + l15)*32 + fke);
    #pragma unroll
    for (int n = 0; n < 4; ++n)
      bfr[n] = *(const bf16x8*)(Bs + (wc*64 + n*16 + l15)*32 + fke);
    #pragma unroll
    for (int m = 0; m < 4; ++m)
      #pragma unroll
      for (int n = 0; n < 4; ++n)
        acc[m][n] = MFMA(af[m], bfr[n], acc[m][n], 0, 0, 0);
    __syncthreads();
  }

  const int ccol = wc*64 + l15;
  float bv[4];
  #pragma unroll
  for (int n = 0; n < 4; ++n) bv[n] = bias[n0 + ccol + n*16];
  #pragma unroll
  for (int m = 0; m < 4; ++m) {
    #pragma unroll
    for (int i = 0; i < 4; ++i) {
      size_t row = (size_t)(m0 + wr*64 + m*16 + (lane>>4)*4 + i);
      #pragma unroll
      for (int n = 0; n < 4; ++n) {
        float v = (acc[m][n][i] + bv[n]) * scale;
        size_t idx = row * Ndim + (n0 + ccol + n*16);
        if (OUT_BF16) ((u16*)Cout)[idx] = f2bf(v);
        else          ((float*)Cout)[idx] = v;
      }
    }
  }
}

// merged Q/K/V projections with XCD chunk-swizzle (R7-verified)
__global__ __launch_bounds__(256, 2) void gemm_qkv(
    const u16* __restrict__ qx, const u16* __restrict__ kx, const u16* __restrict__ vx,
    const u16* __restrict__ wqm, const u16* __restrict__ wkm, const u16* __restrict__ wvm,
    const float* __restrict__ qbv, const float* __restrict__ kbv, const float* __restrict__ vbv,
    u16* __restrict__ qo, u16* __restrict__ ko, u16* __restrict__ vo) {
  __shared__ alignas(16) u16 As[128*32];
  __shared__ alignas(16) u16 Bs[128*32];
  const int flat = blockIdx.x + blockIdx.y * 8 + blockIdx.z * 512;  // 0..1535
  const int j = flat & 7, s = flat >> 3;        // XCD, slot within XCD
  const int c = 3*j + (s >> 6), i = s & 63;     // chunk 0..23, block in chunk
  const int nx = i & 7, yy = ((c & 7) << 3) + (i >> 3);
  const int z = c >> 3;
  const u16* A = z == 0 ? qx : z == 1 ? kx : vx;
  const u16* W = z == 0 ? wqm : z == 1 ? wkm : wvm;
  const float* bias = z == 0 ? qbv : z == 1 ? kbv : vbv;
  u16* C = z == 0 ? qo : z == 1 ? ko : vo;
  const float scale = z == 0 ? 0.125f : 1.0f;
  gemm_body<1>(A, W, bias, C, EE, EE, scale, yy * 128, nx * 128, As, Bs);
}

__global__ __launch_bounds__(256, 2) void gemm_out(
    const u16* __restrict__ A, const u16* __restrict__ W,
    const float* __restrict__ bias, float* __restrict__ Cout) {
  __shared__ alignas(16) u16 As[128*32];
  __shared__ alignas(16) u16 Bs[128*32];
  const int flat = blockIdx.x + blockIdx.y * 8;   // 0..511
  const int j = flat & 7, s = flat >> 3;          // XCD, slot 0..63
  const int nx = s & 7, yy = (j << 3) + (s >> 3); // XCD j -> m-panels 8j..8j+7
  gemm_body<0>(A, W, bias, Cout, EE, EE, 1.0f, yy * 128, nx * 128, As, Bs);
}

// ---------------- causal flash attention v7 (paired q-blocks) --------------
// grid (8, H, B) = 512 blocks, 256 thr. Block processes TWO q-blocks
// sequentially: qhi = 15-qlo then qlo -> uniform 34 tiles/block, no causal
// tail (R7: OccupancyPercent 13.5% from load imbalance). Inner loop verbatim
// R7 attn6 (151 us verified): dbuf Ks (slot^(kv&7)), dbuf VTs (subtile XOR),
// per-wave Ps, fixed-max softmax exp(s-12), deferred l-reduction.
__global__ __launch_bounds__(256, 2) void attn7(
    const u16* __restrict__ Q, const u16* __restrict__ K,
    const u16* __restrict__ V, u16* __restrict__ ctx) {
  __shared__ alignas(16) u16 Ks[2][64*64];    // 16384 B
  __shared__ alignas(16) u16 VTs[2][64*64];   // 16384 B
  __shared__ alignas(16) u16 Ps[4][32*64];    // 16384 B  (49152 total)

  const int tid = threadIdx.x, lane = tid & 63, w = tid >> 6;
  const int l15 = lane & 15, l4 = lane >> 4;
  const int qlo = blockIdx.x, h = blockIdx.y, b = blockIdx.z;
  const size_t base = ((size_t)b * SS) * EE + h * DD;

  const int kr  = tid >> 3;         // K-stage row within 32-row half
  const int ksl = tid & 7;          // K-stage 16B slot
  const int rv  = tid >> 2;         // V-load kv row 0..63
  const int vc  = tid & 3;          // V-load d chunk index (d0 = vc*16)

  u16* KsE  = (u16*)Ks;
  u16* VTsE = (u16*)VTs;
  u16* PsE  = (u16*)Ps + w * 2048;  // per-wave 32 rows x 64 (4096 B)

  auto stageK = [&](int t, int bi) {
    #pragma unroll
    for (int i = 0; i < 2; ++i) {
      int row = i*32 + kr;
      gl_lds16(K + base + (size_t)(t*64 + row)*EE + (ksl ^ (row & 7))*8,
               KsE + bi*4096 + i*2048 + tid*8);
    }
  };
  auto vtWrite = [&](int bi, bf16x8 v0, bf16x8 v1) {
    #pragma unroll
    for (int jj = 0; jj < 16; ++jj) {
      u16 val = jj < 8 ? (u16)v0[jj] : (u16)v1[jj - 8];
      int d = vc*16 + jj;
      int sl = (rv >> 3) ^ (jj & 7) ^ (vc << 1);   // (d&7)=jj&7, (d>>4)=vc
      VTsE[bi*4096 + d*64 + sl*8 + (rv & 7)] = val;
    }
  };

  #pragma unroll 1
  for (int pass = 0; pass < 2; ++pass) {
    const int qblk = pass == 0 ? (15 - qlo) : qlo;
    const int q0 = qblk * 128, wq = q0 + w * 32;
    const int ntile = 2 * qblk + 2;

    // Q B-frags (pre-scaled by 1/8 in projection)
    bf16x8 qf[2][2];
    #pragma unroll
    for (int G = 0; G < 2; ++G)
      #pragma unroll
      for (int kc = 0; kc < 2; ++kc)
        qf[G][kc] = *(const bf16x8*)(Q + base + (size_t)(wq + G*16 + l15)*EE + kc*32 + l4*8);

    f32x4 o[2][4] = {};
    float lsum[2] = {0.f, 0.f};

    // ---- prologue: stage tile 0 into buffers 0 ----
    {
      const u16* vs = V + base + (size_t)rv*EE + vc*16;
      bf16x8 v0 = *(const bf16x8*)vs;
      bf16x8 v1 = *(const bf16x8*)(vs + 8);
      stageK(0, 0);
      vtWrite(0, v0, v1);
    }
    __syncthreads();

    for (int t = 0; t < ntile; ++t) {
      const int cur = t & 1;
      const bool havenext = (t + 1 < ntile);
      bf16x8 nv0, nv1;
      if (havenext) {
        const u16* vs = V + base + (size_t)((t+1)*64 + rv)*EE + vc*16;
        nv0 = *(const bf16x8*)vs;
        nv1 = *(const bf16x8*)(vs + 8);
        stageK(t + 1, cur ^ 1);
      }

      const bool active = (wq + 31 >= t*64);
      const bool g0act  = (wq + 15 >= t*64);
      if (active) {
        // ---- QK^T (swapped): A = K rows, B = Q cols ----
        f32x4 sc[2][4] = {};
        #pragma unroll
        for (int nt = 0; nt < 4; ++nt) {
          int row = nt*16 + l15;
          int sw = row & 7;
          const u16* kb = KsE + cur*4096 + row*64;
          bf16x8 kf0 = *(const bf16x8*)(kb + ((l4    ) ^ sw)*8);
          bf16x8 kf1 = *(const bf16x8*)(kb + ((4 + l4) ^ sw)*8);
          sc[1][nt] = MFMA(kf0, qf[1][0], sc[1][nt], 0, 0, 0);
          sc[1][nt] = MFMA(kf1, qf[1][1], sc[1][nt], 0, 0, 0);
          if (g0act) {
            sc[0][nt] = MFMA(kf0, qf[0][0], sc[0][nt], 0, 0, 0);
            sc[0][nt] = MFMA(kf1, qf[0][1], sc[0][nt], 0, 0, 0);
          }
        }

        // ---- fixed-max softmax + packed P write ----
        #pragma unroll
        for (int G = 0; G < 2; ++G) {
          if (G == 0 && !g0act) continue;
          const bool nomask = (t*64 + 63 <= wq + G*16);
          const int qg = wq + G*16 + l15;
          #pragma unroll
          for (int nt = 0; nt < 4; ++nt) {
            float p0 = exp2f(__builtin_fmaf(sc[G][nt][0], 1.44269504f, -17.3123405f));
            float p1 = exp2f(__builtin_fmaf(sc[G][nt][1], 1.44269504f, -17.3123405f));
            float p2 = exp2f(__builtin_fmaf(sc[G][nt][2], 1.44269504f, -17.3123405f));
            float p3 = exp2f(__builtin_fmaf(sc[G][nt][3], 1.44269504f, -17.3123405f));
            if (!nomask) {
              int kvs = t*64 + nt*16 + l4*4;
              if (kvs + 0 > qg) p0 = 0.f;
              if (kvs + 1 > qg) p1 = 0.f;
              if (kvs + 2 > qg) p2 = 0.f;
              if (kvs + 3 > qg) p3 = 0.f;
            }
            lsum[G] += (p0 + p1) + (p2 + p3);
            uint2 pk;
            pk.x = cvtpk(p0, p1);
            pk.y = cvtpk(p2, p3);
            *(uint2*)((char*)PsE + (G*16 + l15)*128
                          + (((nt*2 + (l4 >> 1)) ^ (l15 & 7)) * 16)
                          + (l4 & 1) * 8) = pk;
          }
        }
      }

      // V^T staging for next tile -> other buffer (overlaps with PV below)
      if (havenext) vtWrite(cur ^ 1, nv0, nv1);

      if (active) {
        // ---- PV: A = P rows (q=l15), B = V^T from swizzled VTs ----
        #pragma unroll
        for (int cc = 0; cc < 2; ++cc) {
          bf16x8 pf1 = *(const bf16x8*)((char*)PsE + (16 + l15)*128
                                       + (((cc*4 + l4) ^ (l15 & 7)) * 16));
          bf16x8 pf0;
          if (g0act)
            pf0 = *(const bf16x8*)((char*)PsE + l15*128
                                       + (((cc*4 + l4) ^ (l15 & 7)) * 16));
          #pragma unroll
          for (int dm = 0; dm < 4; ++dm) {
            int sl = (cc*4 + l4) ^ (l15 & 7) ^ (dm << 1);
            bf16x8 vfv = *(const bf16x8*)(VTsE + cur*4096 + (dm*16 + l15)*64 + sl*8);
            o[1][dm] = MFMA(pf1, vfv, o[1][dm], 0, 0, 0);
            if (g0act) o[0][dm] = MFMA(pf0, vfv, o[0][dm], 0, 0, 0);
          }
        }
      }
      __syncthreads();   // single barrier: t+1 staging (K gl_lds + V^T) visible
    }

    // deferred l reduction (lane holds partial for q = l15; sum over l4 groups)
    #pragma unroll
    for (int G = 0; G < 2; ++G) {
      float r = lsum[G];
      r += __shfl_xor(r, 16);
      r += __shfl_xor(r, 32);
      lsum[G] = 1.0f / r;
    }

    // output: o[G][dm][i] at q = wq+G*16+l4*4+i, d = dm*16+l15
    #pragma unroll
    for (int G = 0; G < 2; ++G)
      #pragma unroll
      for (int i = 0; i < 4; ++i) {
        float invv = __shfl(lsum[G], l4*4 + i);
        size_t roff = base + (size_t)(wq + G*16 + l4*4 + i) * EE;
        #pragma unroll
        for (int dm = 0; dm < 4; ++dm)
          ctx[roff + dm*16 + l15] = f2bf(o[G][dm][i] * invv);
      }
    // loop-end __syncthreads of tile loop already executed; pass-1 prologue
    // restages buffers 0 safely (all reads of pass-0 buffers completed).
  }
}

// ---------------- launch ----------------
extern "C" void kernel_launch(void* const* d_in, const int* in_sizes, int n_in,
                              void* d_out, int out_size, void* d_ws, size_t ws_size,
                              hipStream_t stream) {
  const float* query = (const float*)d_in[0];
  const float* key   = (const float*)d_in[1];
  const float* value = (const float*)d_in[2];
  const float* q_w = (const float*)d_in[4];
  const float* q_b = (const float*)d_in[5];
  const float* k_w = (const float*)d_in[6];
  const float* k_b = (const float*)d_in[7];
  const float* v_w = (const float*)d_in[8];
  const float* v_b = (const float*)d_in[9];
  const float* o_w = (const float*)d_in[10];
  const float* o_b = (const float*)d_in[11];

  char* ws = (char*)d_ws;
  const size_t XB = (size_t)MM * EE * 2;
  const size_t WB = (size_t)EE * EE * 2;
  u16* qx = (u16*)(ws);
  u16* kx = (u16*)(ws + XB);
  u16* vx = (u16*)(ws + 2*XB);
  u16* wq = (u16*)(ws + 3*XB);
  u16* wk = (u16*)(ws + 3*XB + WB);
  u16* wv = (u16*)(ws + 3*XB + 2*WB);
  u16* wo = (u16*)(ws + 3*XB + 3*WB);
  u16* qp = (u16*)(ws + 3*XB + 4*WB);
  u16* kp = (u16*)(ws + 4*XB + 4*WB);
  u16* vp = (u16*)(ws + 5*XB + 4*WB);
  u16* ctxb = qx;   // reuse: query-cast dead after Q projection

  const int nx8 = MM * EE / 8;   // 2^20
  const int nw8 = EE * EE / 8;   // 2^17
  cast3<<<3*nx8/256, 256, 0, stream>>>(query, key, value, qx, kx, vx);
  cast4<<<4*nw8/256, 256, 0, stream>>>(q_w, k_w, v_w, o_w, wq, wk, wv, wo);

  gemm_qkv<<<dim3(EE/128, MM/128, 3), 256, 0, stream>>>(
      qx, kx, vx, wq, wk, wv, q_b, k_b, v_b, qp, kp, vp);

  attn7<<<dim3(8, HH, BB), 256, 0, stream>>>(qp, kp, vp, ctxb);

  gemm_out<<<dim3(EE/128, MM/128), 256, 0, stream>>>(ctxb, wo, o_b, (float*)d_out);
}

// Round 9
// 197.867 us; speedup vs baseline: 1.7858x; 1.0338x over previous
//
#include <hip/hip_runtime.h>
#include <stdint.h>

#define BB 4
#define SS 2048
#define EE 1024
#define HH 16
#define DD 64
#define MM (BB*SS)   // 8192

typedef unsigned short u16;
typedef __attribute__((ext_vector_type(8))) short bf16x8;
typedef __attribute__((ext_vector_type(4))) float f32x4;

#define MFMA __builtin_amdgcn_mfma_f32_16x16x32_bf16

__device__ __forceinline__ u16 f2bf(float f) {
  union { float f; uint32_t u; } x; x.f = f;
  uint32_t r = (x.u + 0x7fffu + ((x.u >> 16) & 1u)) >> 16;
  return (u16)r;
}

__device__ __forceinline__ uint32_t cvtpk(float lo, float hi) {
  uint32_t r;
  asm volatile("v_cvt_pk_bf16_f32 %0, %1, %2" : "=v"(r) : "v"(lo), "v"(hi));
  return r;
}

__device__ __forceinline__ void gl_lds16(const void* g, void* l) {
  __builtin_amdgcn_global_load_lds(
      (const __attribute__((address_space(1))) uint32_t*)g,
      (__attribute__((address_space(3))) uint32_t*)l, 16, 0, 0);
}

// ---------------- single merged cast fp32 -> bf16 (activations + weights) ---
__global__ __launch_bounds__(256) void cast_all(
    const float* __restrict__ a0, const float* __restrict__ a1,
    const float* __restrict__ a2,
    const float* __restrict__ w0, const float* __restrict__ w1,
    const float* __restrict__ w2, const float* __restrict__ w3,
    u16* __restrict__ da0, u16* __restrict__ da1, u16* __restrict__ da2,
    u16* __restrict__ dw0, u16* __restrict__ dw1,
    u16* __restrict__ dw2, u16* __restrict__ dw3) {
  int i = blockIdx.x * 256 + threadIdx.x;     // [0, 3*2^20 + 4*2^17)
  const float* s; u16* d; int off;
  if (i < 3 * (1 << 20)) {
    int sel = i >> 20; off = i & ((1 << 20) - 1);
    s = sel == 0 ? a0 : sel == 1 ? a1 : a2;
    d = sel == 0 ? da0 : sel == 1 ? da1 : da2;
  } else {
    int k = i - 3 * (1 << 20);
    int sel = k >> 17; off = k & ((1 << 17) - 1);
    s = sel == 0 ? w0 : sel == 1 ? w1 : sel == 2 ? w2 : w3;
    d = sel == 0 ? dw0 : sel == 1 ? dw1 : sel == 2 ? dw2 : dw3;
  }
  const float4* sp = (const float4*)s;
  float4 a = sp[off*2], b = sp[off*2+1];
  union { u16 h[8]; uint4 v; } o;
  o.h[0]=f2bf(a.x); o.h[1]=f2bf(a.y); o.h[2]=f2bf(a.z); o.h[3]=f2bf(a.w);
  o.h[4]=f2bf(b.x); o.h[5]=f2bf(b.y); o.h[6]=f2bf(b.z); o.h[7]=f2bf(b.w);
  *(uint4*)(d + (size_t)off*8) = o.v;
}

// ---------------- GEMM core (R4-verified structure) ----------------
template<int OUT_BF16>
__device__ __forceinline__ void gemm_body(
    const u16* __restrict__ A, const u16* __restrict__ W,
    const float* __restrict__ bias, void* __restrict__ Cout,
    int Ndim, int Kdim, float scale, int m0, int n0,
    u16* As, u16* Bs) {
  const int tid = threadIdx.x;
  const int lane = tid & 63, w = tid >> 6;
  const int wr = w >> 1, wc = w & 1;
  const int srow = tid >> 2;
  const int scol = (tid & 3) * 8;

  f32x4 acc[4][4] = {};

  const u16* ag = A + (size_t)(m0 + srow) * Kdim + scol;
  const u16* bg = W + (size_t)(n0 + srow) * Kdim + scol;
  const size_t rstride = (size_t)64 * Kdim;
  const int l15 = lane & 15;
  const int fke = (lane >> 4) * 8;

  for (int k0 = 0; k0 < Kdim; k0 += 32) {
    gl_lds16(ag + k0,           As + tid*8);
    gl_lds16(ag + k0 + rstride, As + 2048 + tid*8);
    gl_lds16(bg + k0,           Bs + tid*8);
    gl_lds16(bg + k0 + rstride, Bs + 2048 + tid*8);
    __syncthreads();

    bf16x8 af[4], bfr[4];
    #pragma unroll
    for (int m = 0; m < 4; ++m)
      af[m] = *(const bf16x8*)(As + (wr*64 + m*16 + l15)*32 + fke);
    #pragma unroll
    for (int n = 0; n < 4; ++n)
      bfr[n] = *(const bf16x8*)(Bs + (wc*64 + n*16 + l15)*32 + fke);
    #pragma unroll
    for (int m = 0; m < 4; ++m)
      #pragma unroll
      for (int n = 0; n < 4; ++n)
        acc[m][n] = MFMA(af[m], bfr[n], acc[m][n], 0, 0, 0);
    __syncthreads();
  }

  const int ccol = wc*64 + l15;
  float bv[4];
  #pragma unroll
  for (int n = 0; n < 4; ++n) bv[n] = bias[n0 + ccol + n*16];
  #pragma unroll
  for (int m = 0; m < 4; ++m) {
    #pragma unroll
    for (int i = 0; i < 4; ++i) {
      size_t row = (size_t)(m0 + wr*64 + m*16 + (lane>>4)*4 + i);
      #pragma unroll
      for (int n = 0; n < 4; ++n) {
        float v = (acc[m][n][i] + bv[n]) * scale;
        size_t idx = row * Ndim + (n0 + ccol + n*16);
        if (OUT_BF16) ((u16*)Cout)[idx] = f2bf(v);
        else          ((float*)Cout)[idx] = v;
      }
    }
  }
}

// merged Q/K/V projections with XCD chunk-swizzle (R7-verified)
__global__ __launch_bounds__(256, 2) void gemm_qkv(
    const u16* __restrict__ qx, const u16* __restrict__ kx, const u16* __restrict__ vx,
    const u16* __restrict__ wqm, const u16* __restrict__ wkm, const u16* __restrict__ wvm,
    const float* __restrict__ qbv, const float* __restrict__ kbv, const float* __restrict__ vbv,
    u16* __restrict__ qo, u16* __restrict__ ko, u16* __restrict__ vo) {
  __shared__ alignas(16) u16 As[128*32];
  __shared__ alignas(16) u16 Bs[128*32];
  const int flat = blockIdx.x + blockIdx.y * 8 + blockIdx.z * 512;  // 0..1535
  const int j = flat & 7, s = flat >> 3;        // XCD, slot within XCD
  const int c = 3*j + (s >> 6), i = s & 63;     // chunk 0..23, block in chunk
  const int nx = i & 7, yy = ((c & 7) << 3) + (i >> 3);
  const int z = c >> 3;
  const u16* A = z == 0 ? qx : z == 1 ? kx : vx;
  const u16* W = z == 0 ? wqm : z == 1 ? wkm : wvm;
  const float* bias = z == 0 ? qbv : z == 1 ? kbv : vbv;
  u16* C = z == 0 ? qo : z == 1 ? ko : vo;
  const float scale = z == 0 ? 0.125f : 1.0f;
  gemm_body<1>(A, W, bias, C, EE, EE, scale, yy * 128, nx * 128, As, Bs);
}

__global__ __launch_bounds__(256, 2) void gemm_out(
    const u16* __restrict__ A, const u16* __restrict__ W,
    const float* __restrict__ bias, float* __restrict__ Cout) {
  __shared__ alignas(16) u16 As[128*32];
  __shared__ alignas(16) u16 Bs[128*32];
  const int flat = blockIdx.x + blockIdx.y * 8;   // 0..511
  const int j = flat & 7, s = flat >> 3;          // XCD, slot 0..63
  const int nx = s & 7, yy = (j << 3) + (s >> 3); // XCD j -> m-panels 8j..8j+7
  gemm_body<0>(A, W, bias, Cout, EE, EE, 1.0f, yy * 128, nx * 128, As, Bs);
}

// ---------------- causal flash attention v8 (paired + XCD panel locality) --
// grid 512 x 1D. f -> XCD j = f&7 owns panels j*8..j*8+7 ((b,h) pairs):
// K+V hot set per XCD = 8 x 512 KB = 4 MB = one L2. qlo = block's pair index;
// block runs q-blocks (15-qlo) then qlo (uniform 34 tiles, R8-verified).
// Inner loop verbatim R8 attn7 (97 us verified).
__global__ __launch_bounds__(256, 2) void attn8(
    const u16* __restrict__ Q, const u16* __restrict__ K,
    const u16* __restrict__ V, u16* __restrict__ ctx) {
  __shared__ alignas(16) u16 Ks[2][64*64];    // 16384 B
  __shared__ alignas(16) u16 VTs[2][64*64];   // 16384 B
  __shared__ alignas(16) u16 Ps[4][32*64];    // 16384 B  (49152 total)

  const int tid = threadIdx.x, lane = tid & 63, w = tid >> 6;
  const int l15 = lane & 15, l4 = lane >> 4;

  const int f = blockIdx.x;               // 0..511
  const int j = f & 7, s = f >> 3;        // XCD, slot
  const int qlo = s & 7;
  const int panel = j * 8 + (s >> 3);     // 0..63
  const int h = panel & 15, b = panel >> 4;
  const size_t base = ((size_t)b * SS) * EE + h * DD;

  const int kr  = tid >> 3;         // K-stage row within 32-row half
  const int ksl = tid & 7;          // K-stage 16B slot
  const int rv  = tid >> 2;         // V-load kv row 0..63
  const int vc  = tid & 3;          // V-load d chunk index (d0 = vc*16)

  u16* KsE  = (u16*)Ks;
  u16* VTsE = (u16*)VTs;
  u16* PsE  = (u16*)Ps + w * 2048;  // per-wave 32 rows x 64 (4096 B)

  auto stageK = [&](int t, int bi) {
    #pragma unroll
    for (int i = 0; i < 2; ++i) {
      int row = i*32 + kr;
      gl_lds16(K + base + (size_t)(t*64 + row)*EE + (ksl ^ (row & 7))*8,
               KsE + bi*4096 + i*2048 + tid*8);
    }
  };
  auto vtWrite = [&](int bi, bf16x8 v0, bf16x8 v1) {
    #pragma unroll
    for (int jj = 0; jj < 16; ++jj) {
      u16 val = jj < 8 ? (u16)v0[jj] : (u16)v1[jj - 8];
      int d = vc*16 + jj;
      int sl = (rv >> 3) ^ (jj & 7) ^ (vc << 1);   // (d&7)=jj&7, (d>>4)=vc
      VTsE[bi*4096 + d*64 + sl*8 + (rv & 7)] = val;
    }
  };

  #pragma unroll 1
  for (int pass = 0; pass < 2; ++pass) {
    const int qblk = pass == 0 ? (15 - qlo) : qlo;
    const int q0 = qblk * 128, wq = q0 + w * 32;
    const int ntile = 2 * qblk + 2;

    // Q B-frags (pre-scaled by 1/8 in projection)
    bf16x8 qf[2][2];
    #pragma unroll
    for (int G = 0; G < 2; ++G)
      #pragma unroll
      for (int kc = 0; kc < 2; ++kc)
        qf[G][kc] = *(const bf16x8*)(Q + base + (size_t)(wq + G*16 + l15)*EE + kc*32 + l4*8);

    f32x4 o[2][4] = {};
    float lsum[2] = {0.f, 0.f};

    // ---- prologue: stage tile 0 into buffers 0 ----
    {
      const u16* vs = V + base + (size_t)rv*EE + vc*16;
      bf16x8 v0 = *(const bf16x8*)vs;
      bf16x8 v1 = *(const bf16x8*)(vs + 8);
      stageK(0, 0);
      vtWrite(0, v0, v1);
    }
    __syncthreads();

    for (int t = 0; t < ntile; ++t) {
      const int cur = t & 1;
      const bool havenext = (t + 1 < ntile);
      bf16x8 nv0, nv1;
      if (havenext) {
        const u16* vs = V + base + (size_t)((t+1)*64 + rv)*EE + vc*16;
        nv0 = *(const bf16x8*)vs;
        nv1 = *(const bf16x8*)(vs + 8);
        stageK(t + 1, cur ^ 1);
      }

      const bool active = (wq + 31 >= t*64);
      const bool g0act  = (wq + 15 >= t*64);
      if (active) {
        // ---- QK^T (swapped): A = K rows, B = Q cols ----
        f32x4 sc[2][4] = {};
        #pragma unroll
        for (int nt = 0; nt < 4; ++nt) {
          int row = nt*16 + l15;
          int sw = row & 7;
          const u16* kb = KsE + cur*4096 + row*64;
          bf16x8 kf0 = *(const bf16x8*)(kb + ((l4    ) ^ sw)*8);
          bf16x8 kf1 = *(const bf16x8*)(kb + ((4 + l4) ^ sw)*8);
          sc[1][nt] = MFMA(kf0, qf[1][0], sc[1][nt], 0, 0, 0);
          sc[1][nt] = MFMA(kf1, qf[1][1], sc[1][nt], 0, 0, 0);
          if (g0act) {
            sc[0][nt] = MFMA(kf0, qf[0][0], sc[0][nt], 0, 0, 0);
            sc[0][nt] = MFMA(kf1, qf[0][1], sc[0][nt], 0, 0, 0);
          }
        }

        // ---- fixed-max softmax + packed P write ----
        #pragma unroll
        for (int G = 0; G < 2; ++G) {
          if (G == 0 && !g0act) continue;
          const bool nomask = (t*64 + 63 <= wq + G*16);
          const int qg = wq + G*16 + l15;
          #pragma unroll
          for (int nt = 0; nt < 4; ++nt) {
            float p0 = exp2f(__builtin_fmaf(sc[G][nt][0], 1.44269504f, -17.3123405f));
            float p1 = exp2f(__builtin_fmaf(sc[G][nt][1], 1.44269504f, -17.3123405f));
            float p2 = exp2f(__builtin_fmaf(sc[G][nt][2], 1.44269504f, -17.3123405f));
            float p3 = exp2f(__builtin_fmaf(sc[G][nt][3], 1.44269504f, -17.3123405f));
            if (!nomask) {
              int kvs = t*64 + nt*16 + l4*4;
              if (kvs + 0 > qg) p0 = 0.f;
              if (kvs + 1 > qg) p1 = 0.f;
              if (kvs + 2 > qg) p2 = 0.f;
              if (kvs + 3 > qg) p3 = 0.f;
            }
            lsum[G] += (p0 + p1) + (p2 + p3);
            uint2 pk;
            pk.x = cvtpk(p0, p1);
            pk.y = cvtpk(p2, p3);
            *(uint2*)((char*)PsE + (G*16 + l15)*128
                          + (((nt*2 + (l4 >> 1)) ^ (l15 & 7)) * 16)
                          + (l4 & 1) * 8) = pk;
          }
        }
      }

      // V^T staging for next tile -> other buffer (overlaps with PV below)
      if (havenext) vtWrite(cur ^ 1, nv0, nv1);

      if (active) {
        // ---- PV: A = P rows (q=l15), B = V^T from swizzled VTs ----
        #pragma unroll
        for (int cc = 0; cc < 2; ++cc) {
          bf16x8 pf1 = *(const bf16x8*)((char*)PsE + (16 + l15)*128
                                       + (((cc*4 + l4) ^ (l15 & 7)) * 16));
          bf16x8 pf0;
          if (g0act)
            pf0 = *(const bf16x8*)((char*)PsE + l15*128
                                       + (((cc*4 + l4) ^ (l15 & 7)) * 16));
          #pragma unroll
          for (int dm = 0; dm < 4; ++dm) {
            int sl = (cc*4 + l4) ^ (l15 & 7) ^ (dm << 1);
            bf16x8 vfv = *(const bf16x8*)(VTsE + cur*4096 + (dm*16 + l15)*64 + sl*8);
            o[1][dm] = MFMA(pf1, vfv, o[1][dm], 0, 0, 0);
            if (g0act) o[0][dm] = MFMA(pf0, vfv, o[0][dm], 0, 0, 0);
          }
        }
      }
      __syncthreads();   // single barrier: t+1 staging (K gl_lds + V^T) visible
    }

    // deferred l reduction (lane holds partial for q = l15; sum over l4 groups)
    #pragma unroll
    for (int G = 0; G < 2; ++G) {
      float r = lsum[G];
      r += __shfl_xor(r, 16);
      r += __shfl_xor(r, 32);
      lsum[G] = 1.0f / r;
    }

    // output: o[G][dm][i] at q = wq+G*16+l4*4+i, d = dm*16+l15
    #pragma unroll
    for (int G = 0; G < 2; ++G)
      #pragma unroll
      for (int i = 0; i < 4; ++i) {
        float invv = __shfl(lsum[G], l4*4 + i);
        size_t roff = base + (size_t)(wq + G*16 + l4*4 + i) * EE;
        #pragma unroll
        for (int dm = 0; dm < 4; ++dm)
          ctx[roff + dm*16 + l15] = f2bf(o[G][dm][i] * invv);
      }
  }
}

// ---------------- launch ----------------
extern "C" void kernel_launch(void* const* d_in, const int* in_sizes, int n_in,
                              void* d_out, int out_size, void* d_ws, size_t ws_size,
                              hipStream_t stream) {
  const float* query = (const float*)d_in[0];
  const float* key   = (const float*)d_in[1];
  const float* value = (const float*)d_in[2];
  const float* q_w = (const float*)d_in[4];
  const float* q_b = (const float*)d_in[5];
  const float* k_w = (const float*)d_in[6];
  const float* k_b = (const float*)d_in[7];
  const float* v_w = (const float*)d_in[8];
  const float* v_b = (const float*)d_in[9];
  const float* o_w = (const float*)d_in[10];
  const float* o_b = (const float*)d_in[11];

  char* ws = (char*)d_ws;
  const size_t XB = (size_t)MM * EE * 2;
  const size_t WB = (size_t)EE * EE * 2;
  u16* qx = (u16*)(ws);
  u16* kx = (u16*)(ws + XB);
  u16* vx = (u16*)(ws + 2*XB);
  u16* wq = (u16*)(ws + 3*XB);
  u16* wk = (u16*)(ws + 3*XB + WB);
  u16* wv = (u16*)(ws + 3*XB + 2*WB);
  u16* wo = (u16*)(ws + 3*XB + 3*WB);
  u16* qp = (u16*)(ws + 3*XB + 4*WB);
  u16* kp = (u16*)(ws + 4*XB + 4*WB);
  u16* vp = (u16*)(ws + 5*XB + 4*WB);
  u16* ctxb = qx;   // reuse: query-cast dead after Q projection

  const int ncast = 3 * (1 << 20) + 4 * (1 << 17);   // 3.67M threads
  cast_all<<<ncast/256, 256, 0, stream>>>(query, key, value,
                                          q_w, k_w, v_w, o_w,
                                          qx, kx, vx, wq, wk, wv, wo);

  gemm_qkv<<<dim3(EE/128, MM/128, 3), 256, 0, stream>>>(
      qx, kx, vx, wq, wk, wv, q_b, k_b, v_b, qp, kp, vp);

  attn8<<<512, 256, 0, stream>>>(qp, kp, vp, ctxb);

  gemm_out<<<dim3(EE/128, MM/128), 256, 0, stream>>>(ctxb, wo, o_b, (float*)d_out);
}

// Round 10
// 183.854 us; speedup vs baseline: 1.9219x; 1.0762x over previous
//
#include <hip/hip_runtime.h>
#include <stdint.h>

#define BB 4
#define SS 2048
#define EE 1024
#define HH 16
#define DD 64
#define MM (BB*SS)   // 8192

typedef unsigned short u16;
typedef __attribute__((ext_vector_type(8))) short bf16x8;
typedef __attribute__((ext_vector_type(4))) float f32x4;

#define MFMA __builtin_amdgcn_mfma_f32_16x16x32_bf16

#if __has_builtin(__builtin_amdgcn_exp2f)
#define EXP2(x) __builtin_amdgcn_exp2f(x)
#else
#define EXP2(x) exp2f(x)
#endif

__device__ __forceinline__ u16 f2bf(float f) {
  union { float f; uint32_t u; } x; x.f = f;
  uint32_t r = (x.u + 0x7fffu + ((x.u >> 16) & 1u)) >> 16;
  return (u16)r;
}

__device__ __forceinline__ uint32_t cvtpk(float lo, float hi) {
  uint32_t r;
  asm volatile("v_cvt_pk_bf16_f32 %0, %1, %2" : "=v"(r) : "v"(lo), "v"(hi));
  return r;
}

__device__ __forceinline__ void gl_lds16(const void* g, void* l) {
  __builtin_amdgcn_global_load_lds(
      (const __attribute__((address_space(1))) uint32_t*)g,
      (__attribute__((address_space(3))) uint32_t*)l, 16, 0, 0);
}

// ---------------- single merged cast fp32 -> bf16 (activations + weights) ---
__global__ __launch_bounds__(256) void cast_all(
    const float* __restrict__ a0, const float* __restrict__ a1,
    const float* __restrict__ a2,
    const float* __restrict__ w0, const float* __restrict__ w1,
    const float* __restrict__ w2, const float* __restrict__ w3,
    u16* __restrict__ da0, u16* __restrict__ da1, u16* __restrict__ da2,
    u16* __restrict__ dw0, u16* __restrict__ dw1,
    u16* __restrict__ dw2, u16* __restrict__ dw3) {
  int i = blockIdx.x * 256 + threadIdx.x;     // [0, 3*2^20 + 4*2^17)
  const float* s; u16* d; int off;
  if (i < 3 * (1 << 20)) {
    int sel = i >> 20; off = i & ((1 << 20) - 1);
    s = sel == 0 ? a0 : sel == 1 ? a1 : a2;
    d = sel == 0 ? da0 : sel == 1 ? da1 : da2;
  } else {
    int k = i - 3 * (1 << 20);
    int sel = k >> 17; off = k & ((1 << 17) - 1);
    s = sel == 0 ? w0 : sel == 1 ? w1 : sel == 2 ? w2 : w3;
    d = sel == 0 ? dw0 : sel == 1 ? dw1 : sel == 2 ? dw2 : dw3;
  }
  const float4* sp = (const float4*)s;
  float4 a = sp[off*2], b = sp[off*2+1];
  union { u16 h[8]; uint4 v; } o;
  o.h[0]=f2bf(a.x); o.h[1]=f2bf(a.y); o.h[2]=f2bf(a.z); o.h[3]=f2bf(a.w);
  o.h[4]=f2bf(b.x); o.h[5]=f2bf(b.y); o.h[6]=f2bf(b.z); o.h[7]=f2bf(b.w);
  *(uint4*)(d + (size_t)off*8) = o.v;
}

// ---------------- GEMM core (R4-verified structure) ----------------
template<int OUT_BF16>
__device__ __forceinline__ void gemm_body(
    const u16* __restrict__ A, const u16* __restrict__ W,
    const float* __restrict__ bias, void* __restrict__ Cout,
    int Ndim, int Kdim, float scale, int m0, int n0,
    u16* As, u16* Bs) {
  const int tid = threadIdx.x;
  const int lane = tid & 63, w = tid >> 6;
  const int wr = w >> 1, wc = w & 1;
  const int srow = tid >> 2;
  const int scol = (tid & 3) * 8;

  f32x4 acc[4][4] = {};

  const u16* ag = A + (size_t)(m0 + srow) * Kdim + scol;
  const u16* bg = W + (size_t)(n0 + srow) * Kdim + scol;
  const size_t rstride = (size_t)64 * Kdim;
  const int l15 = lane & 15;
  const int fke = (lane >> 4) * 8;

  for (int k0 = 0; k0 < Kdim; k0 += 32) {
    gl_lds16(ag + k0,           As + tid*8);
    gl_lds16(ag + k0 + rstride, As + 2048 + tid*8);
    gl_lds16(bg + k0,           Bs + tid*8);
    gl_lds16(bg + k0 + rstride, Bs + 2048 + tid*8);
    __syncthreads();

    bf16x8 af[4], bfr[4];
    #pragma unroll
    for (int m = 0; m < 4; ++m)
      af[m] = *(const bf16x8*)(As + (wr*64 + m*16 + l15)*32 + fke);
    #pragma unroll
    for (int n = 0; n < 4; ++n)
      bfr[n] = *(const bf16x8*)(Bs + (wc*64 + n*16 + l15)*32 + fke);
    #pragma unroll
    for (int m = 0; m < 4; ++m)
      #pragma unroll
      for (int n = 0; n < 4; ++n)
        acc[m][n] = MFMA(af[m], bfr[n], acc[m][n], 0, 0, 0);
    __syncthreads();
  }

  const int ccol = wc*64 + l15;
  float bv[4];
  #pragma unroll
  for (int n = 0; n < 4; ++n) bv[n] = bias[n0 + ccol + n*16];
  #pragma unroll
  for (int m = 0; m < 4; ++m) {
    #pragma unroll
    for (int i = 0; i < 4; ++i) {
      size_t row = (size_t)(m0 + wr*64 + m*16 + (lane>>4)*4 + i);
      #pragma unroll
      for (int n = 0; n < 4; ++n) {
        float v = (acc[m][n][i] + bv[n]) * scale;
        size_t idx = row * Ndim + (n0 + ccol + n*16);
        if (OUT_BF16) ((u16*)Cout)[idx] = f2bf(v);
        else          ((float*)Cout)[idx] = v;
      }
    }
  }
}

// merged Q/K/V projections with XCD chunk-swizzle (R7-verified)
__global__ __launch_bounds__(256, 2) void gemm_qkv(
    const u16* __restrict__ qx, const u16* __restrict__ kx, const u16* __restrict__ vx,
    const u16* __restrict__ wqm, const u16* __restrict__ wkm, const u16* __restrict__ wvm,
    const float* __restrict__ qbv, const float* __restrict__ kbv, const float* __restrict__ vbv,
    u16* __restrict__ qo, u16* __restrict__ ko, u16* __restrict__ vo) {
  __shared__ alignas(16) u16 As[128*32];
  __shared__ alignas(16) u16 Bs[128*32];
  const int flat = blockIdx.x + blockIdx.y * 8 + blockIdx.z * 512;  // 0..1535
  const int j = flat & 7, s = flat >> 3;        // XCD, slot within XCD
  const int c = 3*j + (s >> 6), i = s & 63;     // chunk 0..23, block in chunk
  const int nx = i & 7, yy = ((c & 7) << 3) + (i >> 3);
  const int z = c >> 3;
  const u16* A = z == 0 ? qx : z == 1 ? kx : vx;
  const u16* W = z == 0 ? wqm : z == 1 ? wkm : wvm;
  const float* bias = z == 0 ? qbv : z == 1 ? kbv : vbv;
  u16* C = z == 0 ? qo : z == 1 ? ko : vo;
  const float scale = z == 0 ? 0.125f : 1.0f;
  gemm_body<1>(A, W, bias, C, EE, EE, scale, yy * 128, nx * 128, As, Bs);
}

__global__ __launch_bounds__(256, 2) void gemm_out(
    const u16* __restrict__ A, const u16* __restrict__ W,
    const float* __restrict__ bias, float* __restrict__ Cout) {
  __shared__ alignas(16) u16 As[128*32];
  __shared__ alignas(16) u16 Bs[128*32];
  const int flat = blockIdx.x + blockIdx.y * 8;   // 0..511
  const int j = flat & 7, s = flat >> 3;          // XCD, slot 0..63
  const int nx = s & 7, yy = (j << 3) + (s >> 3); // XCD j -> m-panels 8j..8j+7
  gemm_body<0>(A, W, bias, Cout, EE, EE, 1.0f, yy * 128, nx * 128, As, Bs);
}

// ---------------- causal flash attention v9 (pair-iteration quad-buffer) ---
// grid 512 x 1D, XCD panel mapping (R9: FETCH 145->28 MB verified).
// Per loop iteration: TWO 64-kv tiles from pairbuf cur, ONE barrier
// (R9 analysis: ~3280 cyc/tile wall vs ~900 cyc work -> barrier/drain bound).
// Ks/VTs: [2 pairbuf][2 sub][64*64] quad buffers; staging of pair u+1 issued
// at iteration top, vtWrites interleaved between the two computeTiles.
// LDS 81920 B x 2 blocks/CU = 163840 = exact capacity.
// Inner tile math verbatim R8 (92.8 us verified) + __builtin_amdgcn_exp2f.
__global__ __launch_bounds__(256, 2) void attn9(
    const u16* __restrict__ Q, const u16* __restrict__ K,
    const u16* __restrict__ V, u16* __restrict__ ctx) {
  __shared__ alignas(16) u16 Ks[2][2][64*64];    // 32768 B
  __shared__ alignas(16) u16 VTs[2][2][64*64];   // 32768 B
  __shared__ alignas(16) u16 Ps[4][32*64];       // 16384 B

  const int tid = threadIdx.x, lane = tid & 63, w = tid >> 6;
  const int l15 = lane & 15, l4 = lane >> 4;

  const int f = blockIdx.x;               // 0..511
  const int j = f & 7, s = f >> 3;        // XCD, slot
  const int qlo = s & 7;
  const int panel = j * 8 + (s >> 3);     // 0..63
  const int h = panel & 15, b = panel >> 4;
  const size_t base = ((size_t)b * SS) * EE + h * DD;

  const int kr  = tid >> 3;         // K-stage row within 32-row half
  const int ksl = tid & 7;          // K-stage 16B slot
  const int rv  = tid >> 2;         // V-load kv row 0..63
  const int vc  = tid & 3;          // V-load d chunk index (d0 = vc*16)

  u16* KsE  = (u16*)Ks;
  u16* VTsE = (u16*)VTs;
  u16* PsE  = (u16*)Ps + w * 2048;  // per-wave 32 rows x 64 (4096 B)

  auto stageK = [&](int t, int pb, int sub) {
    #pragma unroll
    for (int i = 0; i < 2; ++i) {
      int row = i*32 + kr;
      gl_lds16(K + base + (size_t)(t*64 + row)*EE + (ksl ^ (row & 7))*8,
               KsE + pb*8192 + sub*4096 + i*2048 + tid*8);
    }
  };
  auto vtWrite = [&](int pb, int sub, bf16x8 v0, bf16x8 v1) {
    #pragma unroll
    for (int jj = 0; jj < 16; ++jj) {
      u16 val = jj < 8 ? (u16)v0[jj] : (u16)v1[jj - 8];
      int d = vc*16 + jj;
      int sl = (rv >> 3) ^ (jj & 7) ^ (vc << 1);   // (d&7)=jj&7, (d>>4)=vc
      VTsE[pb*8192 + sub*4096 + d*64 + sl*8 + (rv & 7)] = val;
    }
  };

  #pragma unroll 1
  for (int pass = 0; pass < 2; ++pass) {
    const int qblk = pass == 0 ? (15 - qlo) : qlo;
    const int q0 = qblk * 128, wq = q0 + w * 32;
    const int npairs = qblk + 1;            // pairs of 64-kv tiles

    // Q B-frags (pre-scaled by 1/8 in projection)
    bf16x8 qf[2][2];
    #pragma unroll
    for (int G = 0; G < 2; ++G)
      #pragma unroll
      for (int kc = 0; kc < 2; ++kc)
        qf[G][kc] = *(const bf16x8*)(Q + base + (size_t)(wq + G*16 + l15)*EE + kc*32 + l4*8);

    f32x4 o[2][4] = {};
    float lsum[2] = {0.f, 0.f};

    // one 64-kv tile: QK^T -> fixed-max softmax -> P -> PV (R8-verified math)
    auto computeTile = [&](int t, int pb, int sub) {
      if (wq + 31 < t*64) return;                 // wave fully masked
      const bool g0act = (wq + 15 >= t*64);
      const u16* tileK = KsE + pb*8192 + sub*4096;
      const u16* tileV = VTsE + pb*8192 + sub*4096;

      f32x4 sc[2][4] = {};
      #pragma unroll
      for (int nt = 0; nt < 4; ++nt) {
        int row = nt*16 + l15;
        int sw = row & 7;
        const u16* kb = tileK + row*64;
        bf16x8 kf0 = *(const bf16x8*)(kb + ((l4    ) ^ sw)*8);
        bf16x8 kf1 = *(const bf16x8*)(kb + ((4 + l4) ^ sw)*8);
        sc[1][nt] = MFMA(kf0, qf[1][0], sc[1][nt], 0, 0, 0);
        sc[1][nt] = MFMA(kf1, qf[1][1], sc[1][nt], 0, 0, 0);
        if (g0act) {
          sc[0][nt] = MFMA(kf0, qf[0][0], sc[0][nt], 0, 0, 0);
          sc[0][nt] = MFMA(kf1, qf[0][1], sc[0][nt], 0, 0, 0);
        }
      }

      #pragma unroll
      for (int G = 0; G < 2; ++G) {
        if (G == 0 && !g0act) continue;
        const bool nomask = (t*64 + 63 <= wq + G*16);
        const int qg = wq + G*16 + l15;
        #pragma unroll
        for (int nt = 0; nt < 4; ++nt) {
          float p0 = EXP2(__builtin_fmaf(sc[G][nt][0], 1.44269504f, -17.3123405f));
          float p1 = EXP2(__builtin_fmaf(sc[G][nt][1], 1.44269504f, -17.3123405f));
          float p2 = EXP2(__builtin_fmaf(sc[G][nt][2], 1.44269504f, -17.3123405f));
          float p3 = EXP2(__builtin_fmaf(sc[G][nt][3], 1.44269504f, -17.3123405f));
          if (!nomask) {
            int kvs = t*64 + nt*16 + l4*4;
            if (kvs + 0 > qg) p0 = 0.f;
            if (kvs + 1 > qg) p1 = 0.f;
            if (kvs + 2 > qg) p2 = 0.f;
            if (kvs + 3 > qg) p3 = 0.f;
          }
          lsum[G] += (p0 + p1) + (p2 + p3);
          uint2 pk;
          pk.x = cvtpk(p0, p1);
          pk.y = cvtpk(p2, p3);
          *(uint2*)((char*)PsE + (G*16 + l15)*128
                        + (((nt*2 + (l4 >> 1)) ^ (l15 & 7)) * 16)
                        + (l4 & 1) * 8) = pk;
        }
      }

      #pragma unroll
      for (int cc = 0; cc < 2; ++cc) {
        bf16x8 pf1 = *(const bf16x8*)((char*)PsE + (16 + l15)*128
                                     + (((cc*4 + l4) ^ (l15 & 7)) * 16));
        bf16x8 pf0;
        if (g0act)
          pf0 = *(const bf16x8*)((char*)PsE + l15*128
                                     + (((cc*4 + l4) ^ (l15 & 7)) * 16));
        #pragma unroll
        for (int dm = 0; dm < 4; ++dm) {
          int sl = (cc*4 + l4) ^ (l15 & 7) ^ (dm << 1);
          bf16x8 vfv = *(const bf16x8*)(tileV + (dm*16 + l15)*64 + sl*8);
          o[1][dm] = MFMA(pf1, vfv, o[1][dm], 0, 0, 0);
          if (g0act) o[0][dm] = MFMA(pf0, vfv, o[0][dm], 0, 0, 0);
        }
      }
    };

    // ---- prologue: stage pair 0 (tiles 0,1) into pairbuf 0 ----
    {
      const u16* va = V + base + (size_t)rv*EE + vc*16;
      const u16* vb = V + base + (size_t)(64 + rv)*EE + vc*16;
      bf16x8 a0 = *(const bf16x8*)va, a1 = *(const bf16x8*)(va + 8);
      bf16x8 b0 = *(const bf16x8*)vb, b1 = *(const bf16x8*)(vb + 8);
      stageK(0, 0, 0);
      stageK(1, 0, 1);
      vtWrite(0, 0, a0, a1);
      vtWrite(0, 1, b0, b1);
    }
    __syncthreads();

    for (int u = 0; u < npairs; ++u) {
      const int cur = u & 1;
      const bool havenext = (u + 1 < npairs);
      bf16x8 na0, na1, nb0, nb1;
      if (havenext) {
        const u16* va = V + base + (size_t)((2*u+2)*64 + rv)*EE + vc*16;
        const u16* vb = V + base + (size_t)((2*u+3)*64 + rv)*EE + vc*16;
        na0 = *(const bf16x8*)va; na1 = *(const bf16x8*)(va + 8);
        nb0 = *(const bf16x8*)vb; nb1 = *(const bf16x8*)(vb + 8);
        stageK(2*u+2, cur ^ 1, 0);
        stageK(2*u+3, cur ^ 1, 1);
      }

      computeTile(2*u, cur, 0);
      if (havenext) vtWrite(cur ^ 1, 0, na0, na1);
      computeTile(2*u + 1, cur, 1);
      if (havenext) vtWrite(cur ^ 1, 1, nb0, nb1);
      __syncthreads();   // pair u reads done; pair u+1 staging visible
    }

    // deferred l reduction (lane holds partial for q = l15; sum over l4 groups)
    #pragma unroll
    for (int G = 0; G < 2; ++G) {
      float r = lsum[G];
      r += __shfl_xor(r, 16);
      r += __shfl_xor(r, 32);
      lsum[G] = 1.0f / r;
    }

    // output: o[G][dm][i] at q = wq+G*16+l4*4+i, d = dm*16+l15
    #pragma unroll
    for (int G = 0; G < 2; ++G)
      #pragma unroll
      for (int i = 0; i < 4; ++i) {
        float invv = __shfl(lsum[G], l4*4 + i);
        size_t roff = base + (size_t)(wq + G*16 + l4*4 + i) * EE;
        #pragma unroll
        for (int dm = 0; dm < 4; ++dm)
          ctx[roff + dm*16 + l15] = f2bf(o[G][dm][i] * invv);
      }
  }
}

// ---------------- launch ----------------
extern "C" void kernel_launch(void* const* d_in, const int* in_sizes, int n_in,
                              void* d_out, int out_size, void* d_ws, size_t ws_size,
                              hipStream_t stream) {
  const float* query = (const float*)d_in[0];
  const float* key   = (const float*)d_in[1];
  const float* value = (const float*)d_in[2];
  const float* q_w = (const float*)d_in[4];
  const float* q_b = (const float*)d_in[5];
  const float* k_w = (const float*)d_in[6];
  const float* k_b = (const float*)d_in[7];
  const float* v_w = (const float*)d_in[8];
  const float* v_b = (const float*)d_in[9];
  const float* o_w = (const float*)d_in[10];
  const float* o_b = (const float*)d_in[11];

  char* ws = (char*)d_ws;
  const size_t XB = (size_t)MM * EE * 2;
  const size_t WB = (size_t)EE * EE * 2;
  u16* qx = (u16*)(ws);
  u16* kx = (u16*)(ws + XB);
  u16* vx = (u16*)(ws + 2*XB);
  u16* wq = (u16*)(ws + 3*XB);
  u16* wk = (u16*)(ws + 3*XB + WB);
  u16* wv = (u16*)(ws + 3*XB + 2*WB);
  u16* wo = (u16*)(ws + 3*XB + 3*WB);
  u16* qp = (u16*)(ws + 3*XB + 4*WB);
  u16* kp = (u16*)(ws + 4*XB + 4*WB);
  u16* vp = (u16*)(ws + 5*XB + 4*WB);
  u16* ctxb = qx;   // reuse: query-cast dead after Q projection

  const int ncast = 3 * (1 << 20) + 4 * (1 << 17);   // 3.67M threads
  cast_all<<<ncast/256, 256, 0, stream>>>(query, key, value,
                                          q_w, k_w, v_w, o_w,
                                          qx, kx, vx, wq, wk, wv, wo);

  gemm_qkv<<<dim3(EE/128, MM/128, 3), 256, 0, stream>>>(
      qx, kx, vx, wq, wk, wv, q_b, k_b, v_b, qp, kp, vp);

  attn9<<<512, 256, 0, stream>>>(qp, kp, vp, ctxb);

  gemm_out<<<dim3(EE/128, MM/128), 256, 0, stream>>>(ctxb, wo, o_b, (float*)d_out);
}

// Round 11
// 175.633 us; speedup vs baseline: 2.0118x; 1.0468x over previous
//
#include <hip/hip_runtime.h>
#include <stdint.h>

#define BB 4
#define SS 2048
#define EE 1024
#define HH 16
#define DD 64
#define MM (BB*SS)   // 8192

typedef unsigned short u16;
typedef __attribute__((ext_vector_type(8))) short bf16x8;
typedef __attribute__((ext_vector_type(4))) float f32x4;

#define MFMA __builtin_amdgcn_mfma_f32_16x16x32_bf16

#if __has_builtin(__builtin_amdgcn_exp2f)
#define EXP2(x) __builtin_amdgcn_exp2f(x)
#else
#define EXP2(x) exp2f(x)
#endif

__device__ __forceinline__ u16 f2bf(float f) {
  union { float f; uint32_t u; } x; x.f = f;
  uint32_t r = (x.u + 0x7fffu + ((x.u >> 16) & 1u)) >> 16;
  return (u16)r;
}

__device__ __forceinline__ uint32_t cvtpk(float lo, float hi) {
  uint32_t r;
  asm volatile("v_cvt_pk_bf16_f32 %0, %1, %2" : "=v"(r) : "v"(lo), "v"(hi));
  return r;
}

__device__ __forceinline__ void gl_lds16(const void* g, void* l) {
  __builtin_amdgcn_global_load_lds(
      (const __attribute__((address_space(1))) uint32_t*)g,
      (__attribute__((address_space(3))) uint32_t*)l, 16, 0, 0);
}

// ---------------- weight-only cast fp32 -> bf16 (12 MB total) ----------------
__global__ __launch_bounds__(256) void cast_w(
    const float* __restrict__ s0, const float* __restrict__ s1,
    const float* __restrict__ s2, const float* __restrict__ s3,
    u16* __restrict__ d0, u16* __restrict__ d1,
    u16* __restrict__ d2, u16* __restrict__ d3) {
  int i = blockIdx.x * 256 + threadIdx.x;          // [0, 4*2^17)
  int sel = i >> 17, off = i & ((1 << 17) - 1);
  const float* s = sel == 0 ? s0 : sel == 1 ? s1 : sel == 2 ? s2 : s3;
  u16* d = sel == 0 ? d0 : sel == 1 ? d1 : sel == 2 ? d2 : d3;
  const float4* sp = (const float4*)s;
  float4 a = sp[off*2], b = sp[off*2+1];
  union { u16 h[8]; uint4 v; } o;
  o.h[0]=f2bf(a.x); o.h[1]=f2bf(a.y); o.h[2]=f2bf(a.z); o.h[3]=f2bf(a.w);
  o.h[4]=f2bf(b.x); o.h[5]=f2bf(b.y); o.h[6]=f2bf(b.z); o.h[7]=f2bf(b.w);
  *(uint4*)(d + (size_t)off*8) = o.v;
}

// ---------------- GEMM core ----------------
// A_FP32=1: A staged as raw fp32 via gl_lds16 (slot ^ (row&7) both-sides
// swizzle, attn-verified pattern), converted to bf16 via v_cvt_pk on the
// LDS->fragment read. Deletes the 96 MB activation-cast pass entirely.
// A_FP32=0: R4-verified all-bf16 path (used by gemm_out).
template<int A_FP32, int OUT_BF16>
__device__ __forceinline__ void gemm_body(
    const void* __restrict__ Ap, const u16* __restrict__ W,
    const float* __restrict__ bias, void* __restrict__ Cout,
    int Ndim, int Kdim, float scale, int m0, int n0,
    u16* As, u16* Bs) {
  const int tid = threadIdx.x;
  const int lane = tid & 63, w = tid >> 6;
  const int wr = w >> 1, wc = w & 1;
  const int l15 = lane & 15;
  const int l4 = lane >> 4;
  const int fke = l4 * 8;

  f32x4 acc[4][4] = {};

  // B staging (bf16, R4 pattern)
  const int srow = tid >> 2;
  const int scol = (tid & 3) * 8;
  const u16* bg = W + (size_t)(n0 + srow) * Kdim + scol;
  const size_t rstrideB = (size_t)64 * Kdim;

  // A fp32 staging: 4 issues x 32 rows, 8 slots of 16B (4 floats) per row
  const int ar  = tid >> 3;          // 0..31
  const int asl = tid & 7;           // dest 16B slot
  const int asw = asl ^ (ar & 7);    // swizzled source slot
  const float* agf = nullptr;
  const u16*   agh = nullptr;
  if (A_FP32) agf = (const float*)Ap + (size_t)(m0 + ar) * Kdim + asw * 4;
  else        agh = (const u16*)Ap + (size_t)(m0 + srow) * Kdim + scol;

  char* AsB = (char*)As;

  for (int k0 = 0; k0 < Kdim; k0 += 32) {
    if (A_FP32) {
      #pragma unroll
      for (int i = 0; i < 4; ++i)   // rows i*32+ar; (row&7)==(ar&7) since 32|i*32
        gl_lds16(agf + (size_t)i*32*Kdim + k0, AsB + i*4096 + tid*16);
    } else {
      gl_lds16(agh + k0,                     As + tid*8);
      gl_lds16(agh + k0 + (size_t)64*Kdim,   As + 2048 + tid*8);
    }
    gl_lds16(bg + k0,            Bs + tid*8);
    gl_lds16(bg + k0 + rstrideB, Bs + 2048 + tid*8);
    __syncthreads();

    bf16x8 af[4], bfr[4];
    #pragma unroll
    for (int m = 0; m < 4; ++m) {
      int r = wr*64 + m*16 + l15;
      if (A_FP32) {
        const char* rb = AsB + r*128;
        f32x4 fa = *(const f32x4*)(rb + (((l4*2    ) ^ (r & 7)) * 16));
        f32x4 fb = *(const f32x4*)(rb + (((l4*2 + 1) ^ (r & 7)) * 16));
        union { uint32_t u[4]; bf16x8 v; } cv;
        cv.u[0] = cvtpk(fa[0], fa[1]);
        cv.u[1] = cvtpk(fa[2], fa[3]);
        cv.u[2] = cvtpk(fb[0], fb[1]);
        cv.u[3] = cvtpk(fb[2], fb[3]);
        af[m] = cv.v;
      } else {
        af[m] = *(const bf16x8*)(As + r*32 + fke);
      }
    }
    #pragma unroll
    for (int n = 0; n < 4; ++n)
      bfr[n] = *(const bf16x8*)(Bs + (wc*64 + n*16 + l15)*32 + fke);
    #pragma unroll
    for (int m = 0; m < 4; ++m)
      #pragma unroll
      for (int n = 0; n < 4; ++n)
        acc[m][n] = MFMA(af[m], bfr[n], acc[m][n], 0, 0, 0);
    __syncthreads();
  }

  const int ccol = wc*64 + l15;
  float bv[4];
  #pragma unroll
  for (int n = 0; n < 4; ++n) bv[n] = bias[n0 + ccol + n*16];
  #pragma unroll
  for (int m = 0; m < 4; ++m) {
    #pragma unroll
    for (int i = 0; i < 4; ++i) {
      size_t row = (size_t)(m0 + wr*64 + m*16 + l4*4 + i);
      #pragma unroll
      for (int n = 0; n < 4; ++n) {
        float v = (acc[m][n][i] + bv[n]) * scale;
        size_t idx = row * Ndim + (n0 + ccol + n*16);
        if (OUT_BF16) ((u16*)Cout)[idx] = f2bf(v);
        else          ((float*)Cout)[idx] = v;
      }
    }
  }
}

// merged Q/K/V projections, fp32-A staging, XCD chunk-swizzle.
// Chunk = 8 n-panels x 4 m-panels of one tensor: W bf16 2MB + A fp32 2MB
// = 4MB = one L2. 48 chunks of 32 blocks; XCD j gets chunks 6j..6j+5.
__global__ __launch_bounds__(256, 2) void gemm_qkv(
    const float* __restrict__ qx, const float* __restrict__ kx, const float* __restrict__ vx,
    const u16* __restrict__ wqm, const u16* __restrict__ wkm, const u16* __restrict__ wvm,
    const float* __restrict__ qbv, const float* __restrict__ kbv, const float* __restrict__ vbv,
    u16* __restrict__ qo, u16* __restrict__ ko, u16* __restrict__ vo) {
  __shared__ alignas(16) u16 As[128*64];   // 16 KB (fp32 128 rows x 32 k)
  __shared__ alignas(16) u16 Bs[128*32];   //  8 KB
  const int flat = blockIdx.x + blockIdx.y * 8 + blockIdx.z * 512;  // 0..1535
  const int j = flat & 7, s = flat >> 3;        // XCD, slot 0..191
  const int c = 6*j + (s >> 5), i = s & 31;     // chunk 0..47, block in chunk
  const int nx = i & 7;
  const int my = ((c & 15) << 2) + (i >> 3);    // 0..63
  const int z = c >> 4;
  const float* A = z == 0 ? qx : z == 1 ? kx : vx;
  const u16* W = z == 0 ? wqm : z == 1 ? wkm : wvm;
  const float* bias = z == 0 ? qbv : z == 1 ? kbv : vbv;
  u16* C = z == 0 ? qo : z == 1 ? ko : vo;
  const float scale = z == 0 ? 0.125f : 1.0f;
  gemm_body<1,1>(A, W, bias, C, EE, EE, scale, my * 128, nx * 128, As, Bs);
}

__global__ __launch_bounds__(256, 2) void gemm_out(
    const u16* __restrict__ A, const u16* __restrict__ W,
    const float* __restrict__ bias, float* __restrict__ Cout) {
  __shared__ alignas(16) u16 As[128*32];
  __shared__ alignas(16) u16 Bs[128*32];
  const int flat = blockIdx.x + blockIdx.y * 8;   // 0..511
  const int j = flat & 7, s = flat >> 3;          // XCD, slot 0..63
  const int nx = s & 7, yy = (j << 3) + (s >> 3); // XCD j -> m-panels 8j..8j+7
  gemm_body<0,0>(A, W, bias, Cout, EE, EE, 1.0f, yy * 128, nx * 128, As, Bs);
}

// ---------------- causal flash attention v9 (R10-verified, 75.8 us) --------
__global__ __launch_bounds__(256, 2) void attn9(
    const u16* __restrict__ Q, const u16* __restrict__ K,
    const u16* __restrict__ V, u16* __restrict__ ctx) {
  __shared__ alignas(16) u16 Ks[2][2][64*64];    // 32768 B
  __shared__ alignas(16) u16 VTs[2][2][64*64];   // 32768 B
  __shared__ alignas(16) u16 Ps[4][32*64];       // 16384 B

  const int tid = threadIdx.x, lane = tid & 63, w = tid >> 6;
  const int l15 = lane & 15, l4 = lane >> 4;

  const int f = blockIdx.x;               // 0..511
  const int j = f & 7, s = f >> 3;        // XCD, slot
  const int qlo = s & 7;
  const int panel = j * 8 + (s >> 3);     // 0..63
  const int h = panel & 15, b = panel >> 4;
  const size_t base = ((size_t)b * SS) * EE + h * DD;

  const int kr  = tid >> 3;
  const int ksl = tid & 7;
  const int rv  = tid >> 2;
  const int vc  = tid & 3;

  u16* KsE  = (u16*)Ks;
  u16* VTsE = (u16*)VTs;
  u16* PsE  = (u16*)Ps + w * 2048;

  auto stageK = [&](int t, int pb, int sub) {
    #pragma unroll
    for (int i = 0; i < 2; ++i) {
      int row = i*32 + kr;
      gl_lds16(K + base + (size_t)(t*64 + row)*EE + (ksl ^ (row & 7))*8,
               KsE + pb*8192 + sub*4096 + i*2048 + tid*8);
    }
  };
  auto vtWrite = [&](int pb, int sub, bf16x8 v0, bf16x8 v1) {
    #pragma unroll
    for (int jj = 0; jj < 16; ++jj) {
      u16 val = jj < 8 ? (u16)v0[jj] : (u16)v1[jj - 8];
      int d = vc*16 + jj;
      int sl = (rv >> 3) ^ (jj & 7) ^ (vc << 1);
      VTsE[pb*8192 + sub*4096 + d*64 + sl*8 + (rv & 7)] = val;
    }
  };

  #pragma unroll 1
  for (int pass = 0; pass < 2; ++pass) {
    const int qblk = pass == 0 ? (15 - qlo) : qlo;
    const int q0 = qblk * 128, wq = q0 + w * 32;
    const int npairs = qblk + 1;

    bf16x8 qf[2][2];
    #pragma unroll
    for (int G = 0; G < 2; ++G)
      #pragma unroll
      for (int kc = 0; kc < 2; ++kc)
        qf[G][kc] = *(const bf16x8*)(Q + base + (size_t)(wq + G*16 + l15)*EE + kc*32 + l4*8);

    f32x4 o[2][4] = {};
    float lsum[2] = {0.f, 0.f};

    auto computeTile = [&](int t, int pb, int sub) {
      if (wq + 31 < t*64) return;
      const bool g0act = (wq + 15 >= t*64);
      const u16* tileK = KsE + pb*8192 + sub*4096;
      const u16* tileV = VTsE + pb*8192 + sub*4096;

      f32x4 sc[2][4] = {};
      #pragma unroll
      for (int nt = 0; nt < 4; ++nt) {
        int row = nt*16 + l15;
        int sw = row & 7;
        const u16* kb = tileK + row*64;
        bf16x8 kf0 = *(const bf16x8*)(kb + ((l4    ) ^ sw)*8);
        bf16x8 kf1 = *(const bf16x8*)(kb + ((4 + l4) ^ sw)*8);
        sc[1][nt] = MFMA(kf0, qf[1][0], sc[1][nt], 0, 0, 0);
        sc[1][nt] = MFMA(kf1, qf[1][1], sc[1][nt], 0, 0, 0);
        if (g0act) {
          sc[0][nt] = MFMA(kf0, qf[0][0], sc[0][nt], 0, 0, 0);
          sc[0][nt] = MFMA(kf1, qf[0][1], sc[0][nt], 0, 0, 0);
        }
      }

      #pragma unroll
      for (int G = 0; G < 2; ++G) {
        if (G == 0 && !g0act) continue;
        const bool nomask = (t*64 + 63 <= wq + G*16);
        const int qg = wq + G*16 + l15;
        #pragma unroll
        for (int nt = 0; nt < 4; ++nt) {
          float p0 = EXP2(__builtin_fmaf(sc[G][nt][0], 1.44269504f, -17.3123405f));
          float p1 = EXP2(__builtin_fmaf(sc[G][nt][1], 1.44269504f, -17.3123405f));
          float p2 = EXP2(__builtin_fmaf(sc[G][nt][2], 1.44269504f, -17.3123405f));
          float p3 = EXP2(__builtin_fmaf(sc[G][nt][3], 1.44269504f, -17.3123405f));
          if (!nomask) {
            int kvs = t*64 + nt*16 + l4*4;
            if (kvs + 0 > qg) p0 = 0.f;
            if (kvs + 1 > qg) p1 = 0.f;
            if (kvs + 2 > qg) p2 = 0.f;
            if (kvs + 3 > qg) p3 = 0.f;
          }
          lsum[G] += (p0 + p1) + (p2 + p3);
          uint2 pk;
          pk.x = cvtpk(p0, p1);
          pk.y = cvtpk(p2, p3);
          *(uint2*)((char*)PsE + (G*16 + l15)*128
                        + (((nt*2 + (l4 >> 1)) ^ (l15 & 7)) * 16)
                        + (l4 & 1) * 8) = pk;
        }
      }

      #pragma unroll
      for (int cc = 0; cc < 2; ++cc) {
        bf16x8 pf1 = *(const bf16x8*)((char*)PsE + (16 + l15)*128
                                     + (((cc*4 + l4) ^ (l15 & 7)) * 16));
        bf16x8 pf0;
        if (g0act)
          pf0 = *(const bf16x8*)((char*)PsE + l15*128
                                     + (((cc*4 + l4) ^ (l15 & 7)) * 16));
        #pragma unroll
        for (int dm = 0; dm < 4; ++dm) {
          int sl = (cc*4 + l4) ^ (l15 & 7) ^ (dm << 1);
          bf16x8 vfv = *(const bf16x8*)(tileV + (dm*16 + l15)*64 + sl*8);
          o[1][dm] = MFMA(pf1, vfv, o[1][dm], 0, 0, 0);
          if (g0act) o[0][dm] = MFMA(pf0, vfv, o[0][dm], 0, 0, 0);
        }
      }
    };

    {
      const u16* va = V + base + (size_t)rv*EE + vc*16;
      const u16* vb = V + base + (size_t)(64 + rv)*EE + vc*16;
      bf16x8 a0 = *(const bf16x8*)va, a1 = *(const bf16x8*)(va + 8);
      bf16x8 b0 = *(const bf16x8*)vb, b1 = *(const bf16x8*)(vb + 8);
      stageK(0, 0, 0);
      stageK(1, 0, 1);
      vtWrite(0, 0, a0, a1);
      vtWrite(0, 1, b0, b1);
    }
    __syncthreads();

    for (int u = 0; u < npairs; ++u) {
      const int cur = u & 1;
      const bool havenext = (u + 1 < npairs);
      bf16x8 na0, na1, nb0, nb1;
      if (havenext) {
        const u16* va = V + base + (size_t)((2*u+2)*64 + rv)*EE + vc*16;
        const u16* vb = V + base + (size_t)((2*u+3)*64 + rv)*EE + vc*16;
        na0 = *(const bf16x8*)va; na1 = *(const bf16x8*)(va + 8);
        nb0 = *(const bf16x8*)vb; nb1 = *(const bf16x8*)(vb + 8);
        stageK(2*u+2, cur ^ 1, 0);
        stageK(2*u+3, cur ^ 1, 1);
      }

      computeTile(2*u, cur, 0);
      if (havenext) vtWrite(cur ^ 1, 0, na0, na1);
      computeTile(2*u + 1, cur, 1);
      if (havenext) vtWrite(cur ^ 1, 1, nb0, nb1);
      __syncthreads();
    }

    #pragma unroll
    for (int G = 0; G < 2; ++G) {
      float r = lsum[G];
      r += __shfl_xor(r, 16);
      r += __shfl_xor(r, 32);
      lsum[G] = 1.0f / r;
    }

    #pragma unroll
    for (int G = 0; G < 2; ++G)
      #pragma unroll
      for (int i = 0; i < 4; ++i) {
        float invv = __shfl(lsum[G], l4*4 + i);
        size_t roff = base + (size_t)(wq + G*16 + l4*4 + i) * EE;
        #pragma unroll
        for (int dm = 0; dm < 4; ++dm)
          ctx[roff + dm*16 + l15] = f2bf(o[G][dm][i] * invv);
      }
  }
}

// ---------------- launch ----------------
extern "C" void kernel_launch(void* const* d_in, const int* in_sizes, int n_in,
                              void* d_out, int out_size, void* d_ws, size_t ws_size,
                              hipStream_t stream) {
  const float* query = (const float*)d_in[0];
  const float* key   = (const float*)d_in[1];
  const float* value = (const float*)d_in[2];
  const float* q_w = (const float*)d_in[4];
  const float* q_b = (const float*)d_in[5];
  const float* k_w = (const float*)d_in[6];
  const float* k_b = (const float*)d_in[7];
  const float* v_w = (const float*)d_in[8];
  const float* v_b = (const float*)d_in[9];
  const float* o_w = (const float*)d_in[10];
  const float* o_b = (const float*)d_in[11];

  char* ws = (char*)d_ws;
  const size_t XB = (size_t)MM * EE * 2;   // 16 MB bf16 activation
  const size_t WB = (size_t)EE * EE * 2;   // 2 MB bf16 weight
  u16* wq = (u16*)(ws);
  u16* wk = (u16*)(ws + WB);
  u16* wv = (u16*)(ws + 2*WB);
  u16* wo = (u16*)(ws + 3*WB);
  u16* qp = (u16*)(ws + 4*WB);
  u16* kp = (u16*)(ws + 4*WB + XB);
  u16* vp = (u16*)(ws + 4*WB + 2*XB);
  u16* ctxb = (u16*)(ws + 4*WB + 3*XB);

  const int nw8 = EE * EE / 8;   // 2^17
  cast_w<<<4*nw8/256, 256, 0, stream>>>(q_w, k_w, v_w, o_w, wq, wk, wv, wo);

  gemm_qkv<<<dim3(8, 64, 3), 256, 0, stream>>>(
      query, key, value, wq, wk, wv, q_b, k_b, v_b, qp, kp, vp);

  attn9<<<512, 256, 0, stream>>>(qp, kp, vp, ctxb);

  gemm_out<<<dim3(EE/128, MM/128), 256, 0, stream>>>(ctxb, wo, o_b, (float*)d_out);
}